// Round 1
// baseline (598.758 us; speedup 1.0000x reference)
//
#include <hip/hip_runtime.h>
#include <hip/hip_bf16.h>
#include <cstdint>

typedef unsigned short u16;
typedef __attribute__((ext_vector_type(8))) short bf16x8;   // 8 bf16 in 4 VGPRs
typedef __attribute__((ext_vector_type(4))) float f32x4;

#define B_ 4
#define C_ 256
#define N_ 4096
#define M_ 4096
#define LOG2E 1.44269504088896340736f

__device__ __forceinline__ u16 f2bf(float x){            // RNE f32 -> bf16
  unsigned u = __float_as_uint(x);
  u += 0x7fffu + ((u >> 16) & 1u);
  return (u16)(u >> 16);
}
__device__ __forceinline__ float bf2f(u16 h){
  return __uint_as_float(((unsigned)h) << 16);
}

// ---------------- K1: instance-norm stats (mean, rstd) per (b,c) ----------------
__global__ __launch_bounds__(256) void k_stats(const float* __restrict__ q,
                                               const float* __restrict__ k,
                                               float* __restrict__ sq,
                                               float* __restrict__ sk){
  int row = blockIdx.x;            // 0..2047 : first 1024 are q rows, then k rows
  const float* src = (row < 1024) ? (q + (size_t)row * N_)
                                  : (k + (size_t)(row - 1024) * N_);
  float s = 0.f, ss = 0.f;
  for (int i = threadIdx.x; i < N_/4; i += 256){
    float4 v = ((const float4*)src)[i];
    s  += v.x + v.y + v.z + v.w;
    ss += v.x*v.x + v.y*v.y + v.z*v.z + v.w*v.w;
  }
  #pragma unroll
  for (int off = 32; off >= 1; off >>= 1){
    s  += __shfl_down(s, off);
    ss += __shfl_down(ss, off);
  }
  __shared__ float rs[4], rss[4];
  int w = threadIdx.x >> 6;
  if ((threadIdx.x & 63) == 0){ rs[w] = s; rss[w] = ss; }
  __syncthreads();
  if (threadIdx.x == 0){
    s  = rs[0]+rs[1]+rs[2]+rs[3];
    ss = rss[0]+rss[1]+rss[2]+rss[3];
    float m   = s * (1.f/N_);
    float var = ss * (1.f/N_) - m*m;
    float r   = rsqrtf(fmaxf(var, 0.f) + 1e-5f);
    float* dst = (row < 1024) ? (sq + row*2) : (sk + (row-1024)*2);
    dst[0] = m; dst[1] = r;
  }
}

// ---------------- K2: conv1x1 GEMMs (fp32 vector) ----------------
// mode 0: qe  = (Wq @ inorm(q) + bq) * LOG2E -> (N,C) hi/lo bf16
// mode 1: ket = (Wk @ inorm(k) + bk)         -> (M,C) hi/lo bf16  (ke transposed)
// mode 2: se  = (Ws @ k + bs)                -> (C,M) bf16
__global__ __launch_bounds__(256) void k_conv(
    const float* __restrict__ q, const float* __restrict__ kk,
    const float* __restrict__ wq, const float* __restrict__ bq,
    const float* __restrict__ wk, const float* __restrict__ bk,
    const float* __restrict__ wsw, const float* __restrict__ bs,
    const float* __restrict__ sq, const float* __restrict__ sk,
    u16* __restrict__ qeh, u16* __restrict__ qel,
    u16* __restrict__ kth, u16* __restrict__ ktl,
    u16* __restrict__ se)
{
  int spt = blockIdx.x, cot = blockIdx.y, bz = blockIdx.z;
  int b = bz / 3, mode = bz - b*3;
  const float* X; const float* W; const float* bias; const float* st = nullptr;
  if (mode == 0){ X = q  + (size_t)b*C_*N_; W = wq;  bias = bq; st = sq + b*C_*2; }
  else if (mode == 1){ X = kk + (size_t)b*C_*M_; W = wk;  bias = bk; st = sk + b*C_*2; }
  else { X = kk + (size_t)b*C_*M_; W = wsw; bias = bs; }

  __shared__ float Wt[64][17];
  __shared__ float Xt[16][132];
  int tid = threadIdx.x;
  int tco = tid & 15, tsp = tid >> 4;
  int co0 = cot*64, sp0 = spt*128;
  float acc[4][8];
  #pragma unroll
  for (int i=0;i<4;i++)
    #pragma unroll
    for (int j=0;j<8;j++) acc[i][j]=0.f;

  for (int kc = 0; kc < C_; kc += 16){
    { int r = tid >> 2, g = tid & 3;
      float4 wv = *(const float4*)(W + (size_t)(co0+r)*C_ + kc + g*4);
      Wt[r][g*4+0]=wv.x; Wt[r][g*4+1]=wv.y; Wt[r][g*4+2]=wv.z; Wt[r][g*4+3]=wv.w;
    }
    { int r = tid >> 4, cg = (tid & 15)*8;
      const float* xp = X + (size_t)(kc + r)*4096 + sp0 + cg;
      float4 a  = ((const float4*)xp)[0];
      float4 bv = ((const float4*)xp)[1];
      if (mode < 2){
        float mm = st[(kc+r)*2], rr = st[(kc+r)*2+1];
        a.x=(a.x-mm)*rr; a.y=(a.y-mm)*rr; a.z=(a.z-mm)*rr; a.w=(a.w-mm)*rr;
        bv.x=(bv.x-mm)*rr; bv.y=(bv.y-mm)*rr; bv.z=(bv.z-mm)*rr; bv.w=(bv.w-mm)*rr;
      }
      *(float4*)&Xt[r][cg]   = a;
      *(float4*)&Xt[r][cg+4] = bv;
    }
    __syncthreads();
    #pragma unroll
    for (int k2 = 0; k2 < 16; ++k2){
      float a0 = Wt[tco*4+0][k2], a1 = Wt[tco*4+1][k2],
            a2 = Wt[tco*4+2][k2], a3 = Wt[tco*4+3][k2];
      float4 b0 = *(float4*)&Xt[k2][tsp*8];
      float4 b1 = *(float4*)&Xt[k2][tsp*8+4];
      float bb[8] = {b0.x,b0.y,b0.z,b0.w,b1.x,b1.y,b1.z,b1.w};
      #pragma unroll
      for (int j=0;j<8;j++){
        acc[0][j] += a0*bb[j]; acc[1][j] += a1*bb[j];
        acc[2][j] += a2*bb[j]; acc[3][j] += a3*bb[j];
      }
    }
    __syncthreads();
  }
  if (mode == 2){
    #pragma unroll
    for (int i=0;i<4;i++){
      int co = co0 + tco*4 + i;
      float bb = bias[co];
      unsigned p[4];
      #pragma unroll
      for (int j=0;j<4;j++){
        unsigned lo = f2bf(acc[i][2*j]   + bb);
        unsigned hi = f2bf(acc[i][2*j+1] + bb);
        p[j] = lo | (hi << 16);
      }
      *(uint4*)(se + ((size_t)(b*C_) + co)*M_ + sp0 + tsp*8) = make_uint4(p[0],p[1],p[2],p[3]);
    }
  } else {
    u16* oh = (mode==0) ? qeh : kth;
    u16* ol = (mode==0) ? qel : ktl;
    float sc = (mode==0) ? LOG2E : 1.f;
    float bb[4];
    #pragma unroll
    for (int i=0;i<4;i++) bb[i] = bias[co0 + tco*4 + i];
    #pragma unroll
    for (int j=0;j<8;j++){
      int sp = sp0 + tsp*8 + j;
      unsigned h01=0, h23=0, l01=0, l23=0;
      #pragma unroll
      for (int i=0;i<4;i++){
        float v = (acc[i][j] + bb[i]) * sc;
        u16 h = f2bf(v);
        u16 l = f2bf(v - bf2f(h));
        if (i==0){ h01 |= h; l01 |= l; }
        if (i==1){ h01 |= ((unsigned)h)<<16; l01 |= ((unsigned)l)<<16; }
        if (i==2){ h23 |= h; l23 |= l; }
        if (i==3){ h23 |= ((unsigned)h)<<16; l23 |= ((unsigned)l)<<16; }
      }
      size_t base = ((size_t)b*4096 + sp)*C_ + co0 + tco*4;
      *(uint2*)(oh + base) = make_uint2(h01, h23);
      *(uint2*)(ol + base) = make_uint2(l01, l23);
    }
  }
}

// ---------------- K3: fused flash attention + AdaAttN epilogue ----------------
// block: 512 thr (8 waves), 64 q-rows, kv-tile 32, online softmax (exp2 domain)
__global__ __launch_bounds__(512, 2) void k_attn(
    const float* __restrict__ q, const float* __restrict__ stq,
    const u16* __restrict__ qeh, const u16* __restrict__ qel,
    const u16* __restrict__ kth_g, const u16* __restrict__ ktl_g,
    const u16* __restrict__ se_g, float* __restrict__ out)
{
  __shared__ u16 KTH[32*256];      // ket hi tile, XOR-swizzled rows
  __shared__ u16 KTL[32*256];
  __shared__ u16 SET[256*40];      // se tile (C rows x 32 m, padded to 40)
  __shared__ u16 WT[64*40];        // softmax weights bf16 (64 n x 32 m, padded)
  __shared__ float PMX[2][64];
  __shared__ float PSM[2][64];
  __shared__ float MRUN[64];
  __shared__ float LRUN[64];
  __shared__ float SCL[64];

  const int tid = threadIdx.x;
  const int wid = tid >> 6, lane = tid & 63;
  const int l15 = lane & 15, lg = lane >> 4;
  const int nq = wid >> 1, mq = wid & 1;     // QK^T role: L quadrant (nq,mq)
  const int wn = wid >> 2, wc = wid & 3;     // PV role: rows wn*32, cols wc*64
  const int b = blockIdx.y;
  const int n0 = blockIdx.x * 64;

  if (tid < 64){ MRUN[tid] = -1e30f; LRUN[tid] = 0.f; }

  // qe fragments held in registers for the whole block
  bf16x8 qhf[8], qlf[8];
  {
    const u16* qb  = qeh + ((size_t)(b*N_ + n0 + nq*16 + l15)) * C_;
    const u16* qb2 = qel + ((size_t)(b*N_ + n0 + nq*16 + l15)) * C_;
    #pragma unroll
    for (int ks=0; ks<8; ++ks){
      qhf[ks] = *(const bf16x8*)(qb  + ks*32 + lg*8);
      qlf[ks] = *(const bf16x8*)(qb2 + ks*32 + lg*8);
    }
  }

  f32x4 acc_m[2][4], acc_s[2][4];
  #pragma unroll
  for (int i=0;i<2;i++)
    #pragma unroll
    for (int j=0;j<4;j++){ acc_m[i][j] = (f32x4)(0.f); acc_s[i][j] = (f32x4)(0.f); }

  for (int m0 = 0; m0 < M_; m0 += 32){
    __syncthreads();                                   // B1: prev PV done
    #pragma unroll
    for (int it=0; it<2; ++it){                        // stage ket hi/lo (swizzled)
      int g = tid + it*512;
      int row = g >> 5, cg = g & 31;
      const uint4* sh = (const uint4*)(kth_g + ((size_t)(b*M_ + m0 + row))*C_ + cg*8);
      const uint4* sl = (const uint4*)(ktl_g + ((size_t)(b*M_ + m0 + row))*C_ + cg*8);
      int dst = row*512 + ((cg*16) ^ ((row & 15) << 4));
      *(uint4*)((char*)KTH + dst) = *sh;
      *(uint4*)((char*)KTL + dst) = *sl;
    }
    #pragma unroll
    for (int it=0; it<2; ++it){                        // stage se tile (C x 32)
      int g = tid + it*512;
      int row = g >> 2, mg = g & 3;
      const uint4* sp = (const uint4*)(se_g + ((size_t)(b*C_ + row))*M_ + m0 + mg*8);
      *(uint4*)&SET[row*40 + mg*8] = *sp;
    }
    __syncthreads();                                   // B2
    // ---- QK^T: L = Qh*Kh + Ql*Kh + Qh*Kl (fp32 acc) ----
    f32x4 L = (f32x4)(0.f);
    {
      int krow = mq*16 + l15;
      int swz = (krow & 15) << 4;
      #pragma unroll
      for (int ks=0; ks<8; ++ks){
        int off = krow*512 + ((ks*64 + lg*16) ^ swz);
        bf16x8 bh = *(const bf16x8*)((char*)KTH + off);
        bf16x8 bl = *(const bf16x8*)((char*)KTL + off);
        L = __builtin_amdgcn_mfma_f32_16x16x32_bf16(qhf[ks], bh, L, 0,0,0);
        L = __builtin_amdgcn_mfma_f32_16x16x32_bf16(qlf[ks], bh, L, 0,0,0);
        L = __builtin_amdgcn_mfma_f32_16x16x32_bf16(qhf[ks], bl, L, 0,0,0);
      }
    }
    float pm[4];
    #pragma unroll
    for (int r=0;r<4;r++) pm[r] = L[r];
    #pragma unroll
    for (int off=1; off<16; off<<=1){
      #pragma unroll
      for (int r=0;r<4;r++) pm[r] = fmaxf(pm[r], __shfl_xor(pm[r], off));
    }
    if (l15 == 0){
      #pragma unroll
      for (int r=0;r<4;r++) PMX[mq][nq*16 + lg*4 + r] = pm[r];
    }
    __syncthreads();                                   // B3
    if (tid < 64){
      float mo = MRUN[tid];
      float mt = fmaxf(PMX[0][tid], PMX[1][tid]);
      float mn = fmaxf(mo, mt);
      float s  = exp2f(mo - mn);
      MRUN[tid] = mn; SCL[tid] = s; LRUN[tid] *= s;
    }
    __syncthreads();                                   // B4
    // ---- W = exp2(L - m_new) -> bf16; psum from ROUNDED weights ----
    {
      float ps[4];
      #pragma unroll
      for (int r=0;r<4;r++){
        int row = nq*16 + lg*4 + r;
        float w = exp2f(L[r] - MRUN[row]);
        u16 wb = f2bf(w);
        WT[row*40 + mq*16 + l15] = wb;
        ps[r] = bf2f(wb);
      }
      #pragma unroll
      for (int off=1; off<16; off<<=1){
        #pragma unroll
        for (int r=0;r<4;r++) ps[r] += __shfl_xor(ps[r], off);
      }
      if (l15 == 0){
        #pragma unroll
        for (int r=0;r<4;r++) PSM[mq][nq*16 + lg*4 + r] = ps[r];
      }
    }
    #pragma unroll
    for (int fn=0; fn<2; ++fn){                        // rescale accumulators
      #pragma unroll
      for (int r=0;r<4;r++){
        float s = SCL[wn*32 + fn*16 + lg*4 + r];
        #pragma unroll
        for (int fc=0; fc<4; ++fc){ acc_m[fn][fc][r] *= s; acc_s[fn][fc][r] *= s; }
      }
    }
    __syncthreads();                                   // B5
    // ---- PV: mean += W*se ; E[s^2] += W*(se^2 hi) + W*(se^2 lo) ----
    {
      bf16x8 a0, a1;
      {
        int wr = wn*32 + l15;
        a0 = *(const bf16x8*)&WT[wr*40 + lg*8];
        a1 = *(const bf16x8*)&WT[(wr+16)*40 + lg*8];
      }
      #pragma unroll
      for (int fc=0; fc<4; ++fc){
        int crow = wc*64 + fc*16 + l15;
        bf16x8 v = *(const bf16x8*)&SET[crow*40 + lg*8];
        bf16x8 h2, l2;
        #pragma unroll
        for (int i=0;i<8;i++){
          float f = bf2f((u16)v[i]);
          float p = f*f;
          u16 hh = f2bf(p);
          h2[i] = (short)hh;
          l2[i] = (short)f2bf(p - bf2f(hh));
        }
        acc_m[0][fc] = __builtin_amdgcn_mfma_f32_16x16x32_bf16(a0, v,  acc_m[0][fc], 0,0,0);
        acc_m[1][fc] = __builtin_amdgcn_mfma_f32_16x16x32_bf16(a1, v,  acc_m[1][fc], 0,0,0);
        acc_s[0][fc] = __builtin_amdgcn_mfma_f32_16x16x32_bf16(a0, h2, acc_s[0][fc], 0,0,0);
        acc_s[0][fc] = __builtin_amdgcn_mfma_f32_16x16x32_bf16(a0, l2, acc_s[0][fc], 0,0,0);
        acc_s[1][fc] = __builtin_amdgcn_mfma_f32_16x16x32_bf16(a1, h2, acc_s[1][fc], 0,0,0);
        acc_s[1][fc] = __builtin_amdgcn_mfma_f32_16x16x32_bf16(a1, l2, acc_s[1][fc], 0,0,0);
      }
      if (tid < 64) LRUN[tid] += PSM[0][tid] + PSM[1][tid];
    }
  }
  __syncthreads();
  // ---- epilogue: normalize, var=relu(E[s^2]-mean^2), cs = qnorm*std + mean ----
  #pragma unroll
  for (int fn=0; fn<2; ++fn){
    float inv[4];
    #pragma unroll
    for (int r=0;r<4;r++) inv[r] = 1.f / LRUN[wn*32 + fn*16 + lg*4 + r];
    #pragma unroll
    for (int fc=0; fc<4; ++fc){
      int c = wc*64 + fc*16 + l15;
      float mm = stq[(b*C_ + c)*2];
      float rr = stq[(b*C_ + c)*2 + 1];
      size_t base = ((size_t)(b*C_ + c))*(size_t)N_ + (size_t)(n0 + wn*32 + fn*16 + lg*4);
      f32x4 qv = *(const f32x4*)(q + base);
      f32x4 res;
      #pragma unroll
      for (int r=0;r<4;r++){
        float mean = acc_m[fn][fc][r] * inv[r];
        float ms   = acc_s[fn][fc][r] * inv[r];
        float sd   = sqrtf(fmaxf(ms - mean*mean, 0.f));
        float qn   = (qv[r] - mm) * rr;
        res[r] = qn * sd + mean;
      }
      *(f32x4*)(out + base) = res;
    }
  }
}

extern "C" void kernel_launch(void* const* d_in, const int* in_sizes, int n_in,
                              void* d_out, int out_size, void* d_ws, size_t ws_size,
                              hipStream_t stream){
  const float* q   = (const float*)d_in[0];
  const float* k   = (const float*)d_in[1];
  const float* wq  = (const float*)d_in[2];
  const float* bq  = (const float*)d_in[3];
  const float* wk  = (const float*)d_in[4];
  const float* bk  = (const float*)d_in[5];
  const float* wsw = (const float*)d_in[6];
  const float* bs  = (const float*)d_in[7];
  float* out = (float*)d_out;

  char* w = (char*)d_ws;
  float* stq = (float*)w;                       // B*C*2 f32 = 8 KB
  float* stk = (float*)(w + 8192);
  u16* qeh = (u16*)(w + 16384);                 // each B*N*C bf16 = 8 MB
  u16* qel = qeh + (size_t)B_*N_*C_;
  u16* kth = qel + (size_t)B_*N_*C_;
  u16* ktl = kth + (size_t)B_*M_*C_;
  u16* se  = ktl + (size_t)B_*M_*C_;

  k_stats<<<dim3(2048), dim3(256), 0, stream>>>(q, k, stq, stk);
  k_conv<<<dim3(32, 4, 12), dim3(256), 0, stream>>>(q, k, wq, bq, wk, bk, wsw, bs,
                                                    stq, stk, qeh, qel, kth, ktl, se);
  k_attn<<<dim3(64, 4), dim3(512), 0, stream>>>(q, stq, qeh, qel, kth, ktl, se, out);
}

// Round 2
// 494.458 us; speedup vs baseline: 1.2109x; 1.2109x over previous
//
#include <hip/hip_runtime.h>
#include <hip/hip_bf16.h>
#include <cstdint>

typedef unsigned short u16;
typedef __attribute__((ext_vector_type(8))) _Float16 half8;  // 8 f16 in 4 VGPRs
typedef __attribute__((ext_vector_type(4))) float f32x4;

#define B_ 4
#define C_ 256
#define N_ 4096
#define M_ 4096
#define QB 32
#define KVB 32
#define LOG2E 1.44269504088896340736f

__device__ __forceinline__ u16 f2h(float x){
  _Float16 h = (_Float16)x;
  return __builtin_bit_cast(u16, h);
}
__device__ __forceinline__ float h2f(u16 h){
  return (float)__builtin_bit_cast(_Float16, h);
}
__device__ __forceinline__ void gll16(const void* gsrc, void* ldst){
  __builtin_amdgcn_global_load_lds(
      (const __attribute__((address_space(1))) unsigned int*)gsrc,
      (__attribute__((address_space(3))) unsigned int*)ldst, 16, 0, 0);
}

// ---------------- K1: instance-norm stats (mean, rstd) per (b,c) ----------------
__global__ __launch_bounds__(256) void k_stats(const float* __restrict__ q,
                                               const float* __restrict__ k,
                                               float* __restrict__ sq,
                                               float* __restrict__ sk){
  int row = blockIdx.x;            // 0..2047 : first 1024 are q rows, then k rows
  const float* src = (row < 1024) ? (q + (size_t)row * N_)
                                  : (k + (size_t)(row - 1024) * N_);
  float s = 0.f, ss = 0.f;
  for (int i = threadIdx.x; i < N_/4; i += 256){
    float4 v = ((const float4*)src)[i];
    s  += v.x + v.y + v.z + v.w;
    ss += v.x*v.x + v.y*v.y + v.z*v.z + v.w*v.w;
  }
  #pragma unroll
  for (int off = 32; off >= 1; off >>= 1){
    s  += __shfl_down(s, off);
    ss += __shfl_down(ss, off);
  }
  __shared__ float rs[4], rss[4];
  int w = threadIdx.x >> 6;
  if ((threadIdx.x & 63) == 0){ rs[w] = s; rss[w] = ss; }
  __syncthreads();
  if (threadIdx.x == 0){
    s  = rs[0]+rs[1]+rs[2]+rs[3];
    ss = rss[0]+rss[1]+rss[2]+rss[3];
    float m   = s * (1.f/N_);
    float var = ss * (1.f/N_) - m*m;
    float r   = rsqrtf(fmaxf(var, 0.f) + 1e-5f);
    float* dst = (row < 1024) ? (sq + row*2) : (sk + (row-1024)*2);
    dst[0] = m; dst[1] = r;
  }
}

// ---------------- K2: conv1x1 GEMMs (fp32 vector) ----------------
// mode 0: qe  = (Wq @ inorm(q) + bq) * LOG2E -> (N,C) f16
// mode 1: kt  = (Wk @ inorm(k) + bk)         -> (M,C) f16  (ke transposed)
// mode 2: se  = (Ws @ k + bs) -> (C,M) f16 ; s2h/s2l = hi/lo f16 of se^2
__global__ __launch_bounds__(256) void k_conv(
    const float* __restrict__ q, const float* __restrict__ kk,
    const float* __restrict__ wq, const float* __restrict__ bq,
    const float* __restrict__ wk, const float* __restrict__ bk,
    const float* __restrict__ wsw, const float* __restrict__ bs,
    const float* __restrict__ sq, const float* __restrict__ sk,
    u16* __restrict__ qe, u16* __restrict__ kt,
    u16* __restrict__ se, u16* __restrict__ s2h, u16* __restrict__ s2l)
{
  int spt = blockIdx.x, cot = blockIdx.y, bz = blockIdx.z;
  int b = bz / 3, mode = bz - b*3;
  const float* X; const float* W; const float* bias; const float* st = nullptr;
  if (mode == 0){ X = q  + (size_t)b*C_*N_; W = wq;  bias = bq; st = sq + b*C_*2; }
  else if (mode == 1){ X = kk + (size_t)b*C_*M_; W = wk;  bias = bk; st = sk + b*C_*2; }
  else { X = kk + (size_t)b*C_*M_; W = wsw; bias = bs; }

  __shared__ float Wt[64][17];
  __shared__ float Xt[16][132];
  int tid = threadIdx.x;
  int tco = tid & 15, tsp = tid >> 4;
  int co0 = cot*64, sp0 = spt*128;
  float acc[4][8];
  #pragma unroll
  for (int i=0;i<4;i++)
    #pragma unroll
    for (int j=0;j<8;j++) acc[i][j]=0.f;

  for (int kc = 0; kc < C_; kc += 16){
    { int r = tid >> 2, g = tid & 3;
      float4 wv = *(const float4*)(W + (size_t)(co0+r)*C_ + kc + g*4);
      Wt[r][g*4+0]=wv.x; Wt[r][g*4+1]=wv.y; Wt[r][g*4+2]=wv.z; Wt[r][g*4+3]=wv.w;
    }
    { int r = tid >> 4, cg = (tid & 15)*8;
      const float* xp = X + (size_t)(kc + r)*4096 + sp0 + cg;
      float4 a  = ((const float4*)xp)[0];
      float4 bv = ((const float4*)xp)[1];
      if (mode < 2){
        float mm = st[(kc+r)*2], rr = st[(kc+r)*2+1];
        a.x=(a.x-mm)*rr; a.y=(a.y-mm)*rr; a.z=(a.z-mm)*rr; a.w=(a.w-mm)*rr;
        bv.x=(bv.x-mm)*rr; bv.y=(bv.y-mm)*rr; bv.z=(bv.z-mm)*rr; bv.w=(bv.w-mm)*rr;
      }
      *(float4*)&Xt[r][cg]   = a;
      *(float4*)&Xt[r][cg+4] = bv;
    }
    __syncthreads();
    #pragma unroll
    for (int k2 = 0; k2 < 16; ++k2){
      float a0 = Wt[tco*4+0][k2], a1 = Wt[tco*4+1][k2],
            a2 = Wt[tco*4+2][k2], a3 = Wt[tco*4+3][k2];
      float4 b0 = *(float4*)&Xt[k2][tsp*8];
      float4 b1 = *(float4*)&Xt[k2][tsp*8+4];
      float bb[8] = {b0.x,b0.y,b0.z,b0.w,b1.x,b1.y,b1.z,b1.w};
      #pragma unroll
      for (int j=0;j<8;j++){
        acc[0][j] += a0*bb[j]; acc[1][j] += a1*bb[j];
        acc[2][j] += a2*bb[j]; acc[3][j] += a3*bb[j];
      }
    }
    __syncthreads();
  }
  if (mode == 2){
    #pragma unroll
    for (int i=0;i<4;i++){
      int co = co0 + tco*4 + i;
      float bb = bias[co];
      unsigned pse[4], ph[4], pl[4];
      #pragma unroll
      for (int j=0;j<4;j++){
        unsigned w0=0,w1=0,w2=0;
        #pragma unroll
        for (int e=0;e<2;e++){
          float v = acc[i][2*j+e] + bb;
          u16 hs = f2h(v);
          float vf = h2f(hs);
          float s2 = vf*vf;
          u16 hh = f2h(s2);
          u16 hl = f2h(s2 - h2f(hh));
          w0 |= ((unsigned)hs) << (16*e);
          w1 |= ((unsigned)hh) << (16*e);
          w2 |= ((unsigned)hl) << (16*e);
        }
        pse[j]=w0; ph[j]=w1; pl[j]=w2;
      }
      size_t base = ((size_t)(b*C_) + co)*M_ + sp0 + tsp*8;
      *(uint4*)(se  + base) = make_uint4(pse[0],pse[1],pse[2],pse[3]);
      *(uint4*)(s2h + base) = make_uint4(ph[0],ph[1],ph[2],ph[3]);
      *(uint4*)(s2l + base) = make_uint4(pl[0],pl[1],pl[2],pl[3]);
    }
  } else {
    u16* o = (mode==0) ? qe : kt;
    float sc = (mode==0) ? LOG2E : 1.f;
    float bb4[4];
    #pragma unroll
    for (int i=0;i<4;i++) bb4[i] = bias[co0 + tco*4 + i];
    #pragma unroll
    for (int j=0;j<8;j++){
      int sp = sp0 + tsp*8 + j;
      unsigned h01 = (unsigned)f2h((acc[0][j]+bb4[0])*sc)
                   | (((unsigned)f2h((acc[1][j]+bb4[1])*sc))<<16);
      unsigned h23 = (unsigned)f2h((acc[2][j]+bb4[2])*sc)
                   | (((unsigned)f2h((acc[3][j]+bb4[3])*sc))<<16);
      *(uint2*)(o + ((size_t)b*4096 + sp)*C_ + co0 + tco*4) = make_uint2(h01, h23);
    }
  }
}

// ---------------- K3: fused flash attention + AdaAttN epilogue ----------------
// 256 thr (4 waves), 32 q-rows/block, kv-tile 32, grid (128,4) = 512 blocks
__global__ __launch_bounds__(256, 2) void k_attn(
    const float* __restrict__ q, const float* __restrict__ stq,
    const u16* __restrict__ qe_g, const u16* __restrict__ kt_g,
    const u16* __restrict__ se_g, const u16* __restrict__ s2h_g,
    const u16* __restrict__ s2l_g, float* __restrict__ out)
{
  __shared__ u16 KT[KVB*256];      // 16KB, chunk16 ^ (row&15)
  __shared__ u16 SE[C_*KVB];       // 16KB, chunk16 ^ ((c>>1)&3)
  __shared__ u16 S2H[C_*KVB];
  __shared__ u16 S2L[C_*KVB];
  __shared__ u16 WT[QB*KVB];       // 2KB,  chunk16 ^ ((row>>1)&3)
  __shared__ float PMX[2][QB];
  __shared__ float PSM[2][QB];
  __shared__ float MRUN[2][QB];
  __shared__ float LRUN[QB];

  const int tid = threadIdx.x;
  const int wid = tid >> 6, lane = tid & 63;
  const int l15 = lane & 15, lg = lane >> 4;
  const int nq = wid >> 1, mq = wid & 1;     // QK^T quadrant
  const int wc = wid;                        // PV col quadrant (64 c)
  const int b = blockIdx.y;
  const int n0 = blockIdx.x * QB;

  if (tid < QB){ MRUN[0][tid] = -1e30f; LRUN[tid] = 0.f; }

  // q fragments (rows nq*16 + l15, full K=256) held for the whole kernel
  half8 qf[8];
  {
    const u16* qb = qe_g + ((size_t)(b*N_ + n0 + nq*16 + l15))*C_;
    #pragma unroll
    for (int ks=0; ks<8; ++ks) qf[ks] = *(const half8*)(qb + ks*32 + lg*8);
  }

  // staging source byte-offsets (swizzle-inverted so linear LDS = swizzled layout)
  int ktsrc[4], sesrc[4];
  #pragma unroll
  for (int i=0;i<4;i++){
    int lin = (i*4 + wid)*1024 + lane*16;
    int row = lin >> 9, ch = (lin >> 4) & 31;
    ktsrc[i] = row*512 + ((ch ^ (row & 15)) << 4);
    int c = lin >> 6, ch2 = (lin >> 4) & 3;
    sesrc[i] = c*(M_*2) + ((ch2 ^ ((c >> 1) & 3)) << 4);
  }
  const char* ktg = (const char*)kt_g  + (size_t)b*M_*512;
  const char* seg = (const char*)se_g  + (size_t)b*C_*M_*2;
  const char* shg = (const char*)s2h_g + (size_t)b*C_*M_*2;
  const char* slg = (const char*)s2l_g + (size_t)b*C_*M_*2;

  f32x4 acc_m[2][4], acc_s[2][4];
  #pragma unroll
  for (int i=0;i<2;i++)
    #pragma unroll
    for (int j=0;j<4;j++){ acc_m[i][j] = (f32x4)(0.f); acc_s[i][j] = (f32x4)(0.f); }

  for (int m0 = 0; m0 < M_; m0 += KVB){
    const int cur = (m0 >> 5) & 1, nxt = cur ^ 1;
    __syncthreads();                           // B_pre: prev tile consumed
    {
      size_t ko = (size_t)m0*512;
      size_t so = (size_t)m0*2;
      #pragma unroll
      for (int i=0;i<4;i++){
        char* ldst = (char*)KT + (i*4 + wid)*1024;
        gll16(ktg + ko + ktsrc[i], ldst);
      }
      #pragma unroll
      for (int i=0;i<4;i++){
        char* ldst = (char*)SE + (i*4 + wid)*1024;
        gll16(seg + so + sesrc[i], ldst);
      }
      #pragma unroll
      for (int i=0;i<4;i++){
        char* ldst = (char*)S2H + (i*4 + wid)*1024;
        gll16(shg + so + sesrc[i], ldst);
      }
      #pragma unroll
      for (int i=0;i<4;i++){
        char* ldst = (char*)S2L + (i*4 + wid)*1024;
        gll16(slg + so + sesrc[i], ldst);
      }
    }
    __syncthreads();                           // B_staged (drains vmcnt)

    // ---- QK^T (fp16, single pass) ----
    f32x4 L = (f32x4)(0.f);
    {
      int krow = mq*16 + l15;
      int sw = (krow & 15) << 4;
      #pragma unroll
      for (int ks=0; ks<8; ++ks){
        half8 kb = *(const half8*)((const char*)KT + krow*512 + ((ks*64 + lg*16) ^ sw));
        L = __builtin_amdgcn_mfma_f32_16x16x32_f16(qf[ks], kb, L, 0,0,0);
      }
    }
    float pm[4];
    #pragma unroll
    for (int r=0;r<4;r++) pm[r] = L[r];
    #pragma unroll
    for (int off=1; off<16; off<<=1){
      #pragma unroll
      for (int r=0;r<4;r++) pm[r] = fmaxf(pm[r], __shfl_xor(pm[r], off));
    }
    if (l15 == 0){
      #pragma unroll
      for (int r=0;r<4;r++) PMX[mq][nq*16 + lg*4 + r] = pm[r];
    }
    __syncthreads();                           // B3: PMX ready

    // rescale accumulators (redundant per-lane max/scale computation)
    #pragma unroll
    for (int fn=0; fn<2; ++fn){
      #pragma unroll
      for (int r=0;r<4;r++){
        int row = fn*16 + lg*4 + r;
        float mo = MRUN[cur][row];
        float mn = fmaxf(mo, fmaxf(PMX[0][row], PMX[1][row]));
        float s = exp2f(mo - mn);
        #pragma unroll
        for (int fc=0; fc<4; ++fc){ acc_m[fn][fc][r] *= s; acc_s[fn][fc][r] *= s; }
      }
    }
    // W = exp2(L - m_new) -> f16 into WT; row psum from ROUNDED weights
    {
      int col = mq*16 + l15;
      float ps[4];
      #pragma unroll
      for (int r=0;r<4;r++){
        int row = nq*16 + lg*4 + r;
        float mn = fmaxf(MRUN[cur][row], fmaxf(PMX[0][row], PMX[1][row]));
        u16 wb = f2h(exp2f(L[r] - mn));
        int byte = row*64 + ((col & 7)*2) + (((col >> 3) ^ ((row >> 1) & 3)) << 4);
        *(u16*)((char*)WT + byte) = wb;
        ps[r] = h2f(wb);
      }
      #pragma unroll
      for (int off=1; off<16; off<<=1){
        #pragma unroll
        for (int r=0;r<4;r++) ps[r] += __shfl_xor(ps[r], off);
      }
      if (l15 == 0){
        #pragma unroll
        for (int r=0;r<4;r++) PSM[mq][nq*16 + lg*4 + r] = ps[r];
      }
    }
    __syncthreads();                           // B5: WT/PSM ready

    // ---- PV: mean += W*se ; E[s^2] += W*s2h + W*s2l ----
    {
      half8 wf[2];
      #pragma unroll
      for (int fn=0; fn<2; ++fn){
        int row = fn*16 + l15;
        wf[fn] = *(const half8*)((const char*)WT + row*64 + ((lg*16) ^ (((row >> 1) & 3) << 4)));
      }
      #pragma unroll
      for (int fc=0; fc<4; ++fc){
        int c = wc*64 + fc*16 + l15;
        int co = c*64 + ((lg*16) ^ (((c >> 1) & 3) << 4));
        half8 v  = *(const half8*)((const char*)SE  + co);
        half8 h2 = *(const half8*)((const char*)S2H + co);
        half8 l2 = *(const half8*)((const char*)S2L + co);
        acc_m[0][fc] = __builtin_amdgcn_mfma_f32_16x16x32_f16(wf[0], v,  acc_m[0][fc], 0,0,0);
        acc_m[1][fc] = __builtin_amdgcn_mfma_f32_16x16x32_f16(wf[1], v,  acc_m[1][fc], 0,0,0);
        acc_s[0][fc] = __builtin_amdgcn_mfma_f32_16x16x32_f16(wf[0], h2, acc_s[0][fc], 0,0,0);
        acc_s[0][fc] = __builtin_amdgcn_mfma_f32_16x16x32_f16(wf[0], l2, acc_s[0][fc], 0,0,0);
        acc_s[1][fc] = __builtin_amdgcn_mfma_f32_16x16x32_f16(wf[1], h2, acc_s[1][fc], 0,0,0);
        acc_s[1][fc] = __builtin_amdgcn_mfma_f32_16x16x32_f16(wf[1], l2, acc_s[1][fc], 0,0,0);
      }
    }
    // single-warp state update (PSM written before B5; next PMX write after B_staged)
    if (tid < QB){
      float mo = MRUN[cur][tid];
      float mn = fmaxf(mo, fmaxf(PMX[0][tid], PMX[1][tid]));
      MRUN[nxt][tid] = mn;
      LRUN[tid] = LRUN[tid]*exp2f(mo - mn) + PSM[0][tid] + PSM[1][tid];
    }
  }
  __syncthreads();
  // ---- epilogue ----
  #pragma unroll
  for (int fn=0; fn<2; ++fn){
    float inv[4];
    #pragma unroll
    for (int r=0;r<4;r++) inv[r] = 1.f / LRUN[fn*16 + lg*4 + r];
    #pragma unroll
    for (int fc=0; fc<4; ++fc){
      int c = wc*64 + fc*16 + l15;
      float mm = stq[(b*C_ + c)*2];
      float rr = stq[(b*C_ + c)*2 + 1];
      size_t base = ((size_t)(b*C_ + c))*(size_t)N_ + (size_t)(n0 + fn*16 + lg*4);
      f32x4 qv = *(const f32x4*)(q + base);
      f32x4 res;
      #pragma unroll
      for (int r=0;r<4;r++){
        float mean = acc_m[fn][fc][r] * inv[r];
        float ms   = acc_s[fn][fc][r] * inv[r];
        float sd   = sqrtf(fmaxf(ms - mean*mean, 0.f));
        float qn   = (qv[r] - mm) * rr;
        res[r] = qn * sd + mean;
      }
      *(f32x4*)(out + base) = res;
    }
  }
}

extern "C" void kernel_launch(void* const* d_in, const int* in_sizes, int n_in,
                              void* d_out, int out_size, void* d_ws, size_t ws_size,
                              hipStream_t stream){
  const float* q   = (const float*)d_in[0];
  const float* k   = (const float*)d_in[1];
  const float* wq  = (const float*)d_in[2];
  const float* bq  = (const float*)d_in[3];
  const float* wk  = (const float*)d_in[4];
  const float* bk  = (const float*)d_in[5];
  const float* wsw = (const float*)d_in[6];
  const float* bs  = (const float*)d_in[7];
  float* out = (float*)d_out;

  char* w = (char*)d_ws;
  float* stq = (float*)w;                       // B*C*2 f32 = 8 KB
  float* stk = (float*)(w + 8192);
  u16* qe  = (u16*)(w + 16384);                 // each B*4096*256 f16 = 8 MB
  u16* kt  = qe  + (size_t)B_*N_*C_;
  u16* se  = kt  + (size_t)B_*M_*C_;
  u16* s2h = se  + (size_t)B_*M_*C_;
  u16* s2l = s2h + (size_t)B_*M_*C_;

  k_stats<<<dim3(2048), dim3(256), 0, stream>>>(q, k, stq, stk);
  k_conv<<<dim3(32, 4, 12), dim3(256), 0, stream>>>(q, k, wq, bq, wk, bk, wsw, bs,
                                                    stq, stk, qe, kt, se, s2h, s2l);
  k_attn<<<dim3(128, 4), dim3(256), 0, stream>>>(q, stq, qe, kt, se, s2h, s2l, out);
}

// Round 4
// 432.163 us; speedup vs baseline: 1.3855x; 1.1441x over previous
//
#include <hip/hip_runtime.h>
#include <hip/hip_bf16.h>
#include <cstdint>

typedef unsigned short u16;
typedef __attribute__((ext_vector_type(8))) _Float16 half8;  // 8 f16 in 4 VGPRs
typedef __attribute__((ext_vector_type(2))) __fp16 fp16x2;
typedef __attribute__((ext_vector_type(4))) float f32x4;

#define B_ 4
#define C_ 256
#define N_ 4096
#define M_ 4096
#define QB 64
#define KVB 32
#define LOG2E 1.44269504088896340736f

__device__ __forceinline__ u16 f2h(float x){
  _Float16 h = (_Float16)x;
  return __builtin_bit_cast(u16, h);
}
__device__ __forceinline__ float h2f(u16 h){
  return (float)__builtin_bit_cast(_Float16, h);
}
__device__ __forceinline__ unsigned pkrtz(float a, float b){
  fp16x2 h = __builtin_amdgcn_cvt_pkrtz(a, b);
  return __builtin_bit_cast(unsigned, h);
}
__device__ __forceinline__ float sum2(unsigned w){
  fp16x2 h = __builtin_bit_cast(fp16x2, w);
  return (float)h.x + (float)h.y;
}
__device__ __forceinline__ void gll16(const void* gsrc, void* ldst){
  __builtin_amdgcn_global_load_lds(
      (const __attribute__((address_space(1))) unsigned int*)gsrc,
      (__attribute__((address_space(3))) unsigned int*)ldst, 16, 0, 0);
}

// ---------------- K1: instance-norm stats (mean, rstd) per (b,c) ----------------
__global__ __launch_bounds__(256) void k_stats(const float* __restrict__ q,
                                               const float* __restrict__ k,
                                               float* __restrict__ sq,
                                               float* __restrict__ sk){
  int row = blockIdx.x;            // 0..2047 : first 1024 are q rows, then k rows
  const float* src = (row < 1024) ? (q + (size_t)row * N_)
                                  : (k + (size_t)(row - 1024) * N_);
  float s = 0.f, ss = 0.f;
  for (int i = threadIdx.x; i < N_/4; i += 256){
    float4 v = ((const float4*)src)[i];
    s  += v.x + v.y + v.z + v.w;
    ss += v.x*v.x + v.y*v.y + v.z*v.z + v.w*v.w;
  }
  #pragma unroll
  for (int off = 32; off >= 1; off >>= 1){
    s  += __shfl_down(s, off);
    ss += __shfl_down(ss, off);
  }
  __shared__ float rs[4], rss[4];
  int w = threadIdx.x >> 6;
  if ((threadIdx.x & 63) == 0){ rs[w] = s; rss[w] = ss; }
  __syncthreads();
  if (threadIdx.x == 0){
    s  = rs[0]+rs[1]+rs[2]+rs[3];
    ss = rss[0]+rss[1]+rss[2]+rss[3];
    float m   = s * (1.f/N_);
    float var = ss * (1.f/N_) - m*m;
    float r   = rsqrtf(fmaxf(var, 0.f) + 1e-5f);
    float* dst = (row < 1024) ? (sq + row*2) : (sk + (row-1024)*2);
    dst[0] = m; dst[1] = r;
  }
}

// ---------------- K2: conv1x1 GEMMs (fp32 vector) ----------------
__global__ __launch_bounds__(256) void k_conv(
    const float* __restrict__ q, const float* __restrict__ kk,
    const float* __restrict__ wq, const float* __restrict__ bq,
    const float* __restrict__ wk, const float* __restrict__ bk,
    const float* __restrict__ wsw, const float* __restrict__ bs,
    const float* __restrict__ sq, const float* __restrict__ sk,
    u16* __restrict__ qe, u16* __restrict__ kt,
    u16* __restrict__ se, u16* __restrict__ s2h, u16* __restrict__ s2l)
{
  int spt = blockIdx.x, cot = blockIdx.y, bz = blockIdx.z;
  int b = bz / 3, mode = bz - b*3;
  const float* X; const float* W; const float* bias; const float* st = nullptr;
  if (mode == 0){ X = q  + (size_t)b*C_*N_; W = wq;  bias = bq; st = sq + b*C_*2; }
  else if (mode == 1){ X = kk + (size_t)b*C_*M_; W = wk;  bias = bk; st = sk + b*C_*2; }
  else { X = kk + (size_t)b*C_*M_; W = wsw; bias = bs; }

  __shared__ float Wt[64][17];
  __shared__ float Xt[16][132];
  int tid = threadIdx.x;
  int tco = tid & 15, tsp = tid >> 4;
  int co0 = cot*64, sp0 = spt*128;
  float acc[4][8];
  #pragma unroll
  for (int i=0;i<4;i++)
    #pragma unroll
    for (int j=0;j<8;j++) acc[i][j]=0.f;

  for (int kc = 0; kc < C_; kc += 16){
    { int r = tid >> 2, g = tid & 3;
      float4 wv = *(const float4*)(W + (size_t)(co0+r)*C_ + kc + g*4);
      Wt[r][g*4+0]=wv.x; Wt[r][g*4+1]=wv.y; Wt[r][g*4+2]=wv.z; Wt[r][g*4+3]=wv.w;
    }
    { int r = tid >> 4, cg = (tid & 15)*8;
      const float* xp = X + (size_t)(kc + r)*4096 + sp0 + cg;
      float4 a  = ((const float4*)xp)[0];
      float4 bv = ((const float4*)xp)[1];
      if (mode < 2){
        float mm = st[(kc+r)*2], rr = st[(kc+r)*2+1];
        a.x=(a.x-mm)*rr; a.y=(a.y-mm)*rr; a.z=(a.z-mm)*rr; a.w=(a.w-mm)*rr;
        bv.x=(bv.x-mm)*rr; bv.y=(bv.y-mm)*rr; bv.z=(bv.z-mm)*rr; bv.w=(bv.w-mm)*rr;
      }
      *(float4*)&Xt[r][cg]   = a;
      *(float4*)&Xt[r][cg+4] = bv;
    }
    __syncthreads();
    #pragma unroll
    for (int k2 = 0; k2 < 16; ++k2){
      float a0 = Wt[tco*4+0][k2], a1 = Wt[tco*4+1][k2],
            a2 = Wt[tco*4+2][k2], a3 = Wt[tco*4+3][k2];
      float4 b0 = *(float4*)&Xt[k2][tsp*8];
      float4 b1 = *(float4*)&Xt[k2][tsp*8+4];
      float bb[8] = {b0.x,b0.y,b0.z,b0.w,b1.x,b1.y,b1.z,b1.w};
      #pragma unroll
      for (int j=0;j<8;j++){
        acc[0][j] += a0*bb[j]; acc[1][j] += a1*bb[j];
        acc[2][j] += a2*bb[j]; acc[3][j] += a3*bb[j];
      }
    }
    __syncthreads();
  }
  if (mode == 2){
    #pragma unroll
    for (int i=0;i<4;i++){
      int co = co0 + tco*4 + i;
      float bb = bias[co];
      unsigned pse[4], ph[4], pl[4];
      #pragma unroll
      for (int j=0;j<4;j++){
        unsigned w0=0,w1=0,w2=0;
        #pragma unroll
        for (int e=0;e<2;e++){
          float v = acc[i][2*j+e] + bb;
          u16 hs = f2h(v);
          float vf = h2f(hs);
          float s2 = vf*vf;
          u16 hh = f2h(s2);
          u16 hl = f2h(s2 - h2f(hh));
          w0 |= ((unsigned)hs) << (16*e);
          w1 |= ((unsigned)hh) << (16*e);
          w2 |= ((unsigned)hl) << (16*e);
        }
        pse[j]=w0; ph[j]=w1; pl[j]=w2;
      }
      size_t base = ((size_t)(b*C_) + co)*M_ + sp0 + tsp*8;
      *(uint4*)(se  + base) = make_uint4(pse[0],pse[1],pse[2],pse[3]);
      *(uint4*)(s2h + base) = make_uint4(ph[0],ph[1],ph[2],ph[3]);
      *(uint4*)(s2l + base) = make_uint4(pl[0],pl[1],pl[2],pl[3]);
    }
  } else {
    u16* o = (mode==0) ? qe : kt;
    float sc = (mode==0) ? LOG2E : 1.f;
    float bb4[4];
    #pragma unroll
    for (int i=0;i<4;i++) bb4[i] = bias[co0 + tco*4 + i];
    #pragma unroll
    for (int j=0;j<8;j++){
      int sp = sp0 + tsp*8 + j;
      unsigned h01 = (unsigned)f2h((acc[0][j]+bb4[0])*sc)
                   | (((unsigned)f2h((acc[1][j]+bb4[1])*sc))<<16);
      unsigned h23 = (unsigned)f2h((acc[2][j]+bb4[2])*sc)
                   | (((unsigned)f2h((acc[3][j]+bb4[3])*sc))<<16);
      *(uint2*)(o + ((size_t)b*4096 + sp)*C_ + co0 + tco*4) = make_uint2(h01, h23);
    }
  }
}

// ---------------- K3: swapped-QK flash attention + AdaAttN epilogue ----------------
// 256 thr (4 waves), QB=64 q-rows/block, kv-tile 32, grid (64,4)=256 blocks.
// Wave w: QK rows [w*16, w*16+16) (in-register softmax), PV cols [w*64, w*64+64).
__global__ __launch_bounds__(256, 1) void k_attn(
    const float* __restrict__ q, const float* __restrict__ stq,
    const u16* __restrict__ qe_g, const u16* __restrict__ kt_g,
    const u16* __restrict__ se_g, const u16* __restrict__ s2h_g,
    const u16* __restrict__ s2l_g, float* __restrict__ out)
{
  __shared__ u16 KTs[2][KVB*256];     // 16KB x2, chunk16 ^ (row&7)
  __shared__ u16 SEs[2][C_*KVB];      // 16KB x2, linear (c-row major, 64B rows)
  __shared__ u16 S2Hs[2][C_*KVB];
  __shared__ u16 S2Ls[2][C_*KVB];
  __shared__ unsigned WTw[QB*16];     // P weights f16, [row][16 u32 words]
  __shared__ float SRES[QB];
  __shared__ float LRUNS[QB];
  __shared__ int FLG[4];

  const int tid = threadIdx.x;
  const int wid = tid >> 6, lane = tid & 63;
  const int l15 = lane & 15, lg = lane >> 4;
  const int b = blockIdx.y;
  const int n0 = blockIdx.x * QB;

  // Q fragments for this wave's 16 rows (B-operand: lane l15 = q-row col)
  half8 qf[8];
  {
    const u16* qb = qe_g + ((size_t)(b*N_ + n0 + wid*16 + l15))*C_;
    #pragma unroll
    for (int ks=0; ks<8; ++ks) qf[ks] = *(const half8*)(qb + ks*32 + lg*8);
  }

  // staging source byte-offsets (KT pre-swizzled; SE linear)
  int ktsrc[4], sesrc[4];
  #pragma unroll
  for (int i=0;i<4;i++){
    int g = (i*4 + wid)*64 + lane;
    int row = g >> 5, cin = g & 31;
    ktsrc[i] = row*512 + ((cin ^ (row & 7)) << 4);
    int c = g >> 2, mch = g & 3;
    sesrc[i] = c*8192 + mch*16;
  }
  const char* ktg = (const char*)kt_g  + (size_t)b*M_*512;
  const char* seg = (const char*)se_g  + (size_t)b*C_*M_*2;
  const char* shg = (const char*)s2h_g + (size_t)b*C_*M_*2;
  const char* slg = (const char*)s2l_g + (size_t)b*C_*M_*2;

  float m_run = -1e30f, lrun = 0.f;
  f32x4 accm[4][4], accs[4][4];
  #pragma unroll
  for (int i=0;i<4;i++)
    #pragma unroll
    for (int j=0;j<4;j++){ accm[i][j] = (f32x4)(0.f); accs[i][j] = (f32x4)(0.f); }

  // prologue: stage tile 0 into buf 0
  #pragma unroll
  for (int i=0;i<4;i++){
    int o = (i*4 + wid)*1024;
    gll16(ktg + ktsrc[i], (char*)&KTs[0][0] + o);
    gll16(seg + sesrc[i], (char*)&SEs[0][0] + o);
    gll16(shg + sesrc[i], (char*)&S2Hs[0][0] + o);
    gll16(slg + sesrc[i], (char*)&S2Ls[0][0] + o);
  }

  for (int t=0; t<M_/KVB; ++t){
    const int buf = t & 1;
    __syncthreads();                      // B1: stage(t) done (drains vmcnt), prev PV done

    // ---- QK^T swapped: D[m][n], lane holds n=l15, m = lg*4+r (+16) ----
    f32x4 L0 = (f32x4)(0.f), L1 = (f32x4)(0.f);
    {
      const char* ktb = (const char*)&KTs[buf][0];
      #pragma unroll
      for (int ks=0; ks<8; ++ks){
        int ch = ((ks*4 + lg) ^ (l15 & 7)) << 4;
        half8 a0 = *(const half8*)(ktb + l15*512 + ch);
        half8 a1 = *(const half8*)(ktb + (16+l15)*512 + ch);
        L0 = __builtin_amdgcn_mfma_f32_16x16x32_f16(a0, qf[ks], L0, 0,0,0);
        L1 = __builtin_amdgcn_mfma_f32_16x16x32_f16(a1, qf[ks], L1, 0,0,0);
      }
    }
    // ---- in-register online softmax for row l15 ----
    float p[8] = {L0[0],L0[1],L0[2],L0[3],L1[0],L1[1],L1[2],L1[3]};
    float pm = p[0];
    #pragma unroll
    for (int j=1;j<8;j++) pm = fmaxf(pm, p[j]);
    pm = fmaxf(pm, __shfl_xor(pm, 16));
    pm = fmaxf(pm, __shfl_xor(pm, 32));
    int flag = __any(pm > m_run + 8.0f);  // defer-max THR=8 (exp2 domain)
    float sv = 1.0f;
    if (flag){
      float mn = fmaxf(m_run, pm);
      sv = exp2f(m_run - mn);
      m_run = mn;
      lrun *= sv;
    }
    if (lg == 0) SRES[wid*16 + l15] = sv;
    if (lane == 0) FLG[wid] = flag;
    unsigned W0 = pkrtz(exp2f(p[0]-m_run), exp2f(p[1]-m_run));
    unsigned W1 = pkrtz(exp2f(p[2]-m_run), exp2f(p[3]-m_run));
    unsigned W2 = pkrtz(exp2f(p[4]-m_run), exp2f(p[5]-m_run));
    unsigned W3 = pkrtz(exp2f(p[6]-m_run), exp2f(p[7]-m_run));
    {
      int row = wid*16 + l15;
      *(uint2*)&WTw[(row<<4) + (lg<<1)]     = make_uint2(W0, W1);
      *(uint2*)&WTw[(row<<4) + 8 + (lg<<1)] = make_uint2(W2, W3);
    }
    float rs = sum2(W0) + sum2(W1) + sum2(W2) + sum2(W3);  // ROUNDED row-sum
    rs += __shfl_xor(rs, 16);
    rs += __shfl_xor(rs, 32);
    lrun += rs;
    __syncthreads();                      // B2: WT/SRES/FLG ready

    // prefetch next tile (safe: all waves past PV(t-1) since B1)
    if (t+1 < M_/KVB){
      const int nb = buf ^ 1;
      int koff = (t+1)*(KVB*512);
      int soff = (t+1)*(KVB*2);
      #pragma unroll
      for (int i=0;i<4;i++){
        int o = (i*4 + wid)*1024;
        gll16(ktg + koff + ktsrc[i], (char*)&KTs[nb][0] + o);
        gll16(seg + soff + sesrc[i], (char*)&SEs[nb][0] + o);
        gll16(shg + soff + sesrc[i], (char*)&S2Hs[nb][0] + o);
        gll16(slg + soff + sesrc[i], (char*)&S2Ls[nb][0] + o);
      }
    }

    // conditional accumulator rescale (rare after warm-up)
    int bf = FLG[0] | FLG[1] | FLG[2] | FLG[3];
    if (bf){
      #pragma unroll
      for (int rt=0;rt<4;rt++){
        f32x4 s4 = *(const f32x4*)&SRES[rt*16 + lg*4];
        #pragma unroll
        for (int ct=0;ct<4;ct++){
          #pragma unroll
          for (int r=0;r<4;r++){ accm[rt][ct][r] *= s4[r]; accs[rt][ct][r] *= s4[r]; }
        }
      }
    }

    // ---- PV: mean += P*se ; E[s^2] += P*s2h + P*s2l ----
    {
      half8 a[4];
      #pragma unroll
      for (int rt=0;rt<4;rt++)
        a[rt] = *(const half8*)&WTw[((rt*16 + l15)<<4) + (lg<<2)];
      const char* seb = (const char*)&SEs[buf][0];
      const char* shb = (const char*)&S2Hs[buf][0];
      const char* slb = (const char*)&S2Ls[buf][0];
      #pragma unroll
      for (int ct=0;ct<4;ct++){
        int co = (wid*64 + ct*16 + l15)*64 + lg*16;
        half8 v  = *(const half8*)(seb + co);
        half8 h2 = *(const half8*)(shb + co);
        half8 l2 = *(const half8*)(slb + co);
        #pragma unroll
        for (int rt=0;rt<4;rt++){
          accm[rt][ct] = __builtin_amdgcn_mfma_f32_16x16x32_f16(a[rt], v,  accm[rt][ct], 0,0,0);
          accs[rt][ct] = __builtin_amdgcn_mfma_f32_16x16x32_f16(a[rt], h2, accs[rt][ct], 0,0,0);
          accs[rt][ct] = __builtin_amdgcn_mfma_f32_16x16x32_f16(a[rt], l2, accs[rt][ct], 0,0,0);
        }
      }
    }
  }

  if (lg == 0) LRUNS[wid*16 + l15] = lrun;
  __syncthreads();

  // ---- epilogue: normalize, var=relu(E[s^2]-mean^2), cs = qnorm*std + mean ----
  #pragma unroll
  for (int rt=0;rt<4;rt++){
    f32x4 lv = *(const f32x4*)&LRUNS[rt*16 + lg*4];
    f32x4 inv;
    #pragma unroll
    for (int r=0;r<4;r++) inv[r] = 1.f / lv[r];
    #pragma unroll
    for (int ct=0;ct<4;ct++){
      int c = wid*64 + ct*16 + l15;
      float2 st = *(const float2*)(stq + (size_t)(b*C_ + c)*2);
      size_t base = ((size_t)(b*C_ + c))*(size_t)N_ + (size_t)(n0 + rt*16 + lg*4);
      f32x4 qv = *(const f32x4*)(q + base);
      f32x4 res;
      #pragma unroll
      for (int r=0;r<4;r++){
        float mean = accm[rt][ct][r] * inv[r];
        float ms   = accs[rt][ct][r] * inv[r];
        float sd   = sqrtf(fmaxf(ms - mean*mean, 0.f));
        float qn   = (qv[r] - st.x) * st.y;
        res[r] = qn * sd + mean;
      }
      *(f32x4*)(out + base) = res;
    }
  }
}

extern "C" void kernel_launch(void* const* d_in, const int* in_sizes, int n_in,
                              void* d_out, int out_size, void* d_ws, size_t ws_size,
                              hipStream_t stream){
  const float* q   = (const float*)d_in[0];
  const float* k   = (const float*)d_in[1];
  const float* wq  = (const float*)d_in[2];
  const float* bq  = (const float*)d_in[3];
  const float* wk  = (const float*)d_in[4];
  const float* bk  = (const float*)d_in[5];
  const float* wsw = (const float*)d_in[6];
  const float* bs  = (const float*)d_in[7];
  float* out = (float*)d_out;

  char* w = (char*)d_ws;
  float* stq = (float*)w;                       // B*C*2 f32 = 8 KB
  float* stk = (float*)(w + 8192);
  u16* qe  = (u16*)(w + 16384);                 // each B*4096*256 f16 = 8 MB
  u16* kt  = qe  + (size_t)B_*N_*C_;
  u16* se  = kt  + (size_t)B_*M_*C_;
  u16* s2h = se  + (size_t)B_*M_*C_;
  u16* s2l = s2h + (size_t)B_*M_*C_;

  k_stats<<<dim3(2048), dim3(256), 0, stream>>>(q, k, stq, stk);
  k_conv<<<dim3(32, 4, 12), dim3(256), 0, stream>>>(q, k, wq, bq, wk, bk, wsw, bs,
                                                    stq, stk, qe, kt, se, s2h, s2l);
  k_attn<<<dim3(N_/QB, B_), dim3(256), 0, stream>>>(q, stq, qe, kt, se, s2h, s2l, out);
}

// Round 5
// 421.268 us; speedup vs baseline: 1.4213x; 1.0259x over previous
//
#include <hip/hip_runtime.h>
#include <hip/hip_bf16.h>
#include <cstdint>

typedef unsigned short u16;
typedef __attribute__((ext_vector_type(8))) _Float16 half8;  // 8 f16 in 4 VGPRs
typedef __attribute__((ext_vector_type(2))) __fp16 fp16x2;
typedef __attribute__((ext_vector_type(4))) float f32x4;

#define B_ 4
#define C_ 256
#define N_ 4096
#define M_ 4096
#define QB 64
#define KVB 32
#define LOG2E 1.44269504088896340736f

__device__ __forceinline__ u16 f2h(float x){
  _Float16 h = (_Float16)x;
  return __builtin_bit_cast(u16, h);
}
__device__ __forceinline__ float h2f(u16 h){
  return (float)__builtin_bit_cast(_Float16, h);
}
__device__ __forceinline__ unsigned pkrtz(float a, float b){
  fp16x2 h = __builtin_amdgcn_cvt_pkrtz(a, b);
  return __builtin_bit_cast(unsigned, h);
}
__device__ __forceinline__ float sum2(unsigned w){
  fp16x2 h = __builtin_bit_cast(fp16x2, w);
  return (float)h.x + (float)h.y;
}
__device__ __forceinline__ void gll16(const void* gsrc, void* ldst){
  __builtin_amdgcn_global_load_lds(
      (const __attribute__((address_space(1))) unsigned int*)gsrc,
      (__attribute__((address_space(3))) unsigned int*)ldst, 16, 0, 0);
}

// ---------------- K1: instance-norm stats (mean, rstd) per (b,c) ----------------
__global__ __launch_bounds__(256) void k_stats(const float* __restrict__ q,
                                               const float* __restrict__ k,
                                               float* __restrict__ sq,
                                               float* __restrict__ sk){
  int row = blockIdx.x;            // 0..2047 : first 1024 are q rows, then k rows
  const float* src = (row < 1024) ? (q + (size_t)row * N_)
                                  : (k + (size_t)(row - 1024) * N_);
  float s = 0.f, ss = 0.f;
  for (int i = threadIdx.x; i < N_/4; i += 256){
    float4 v = ((const float4*)src)[i];
    s  += v.x + v.y + v.z + v.w;
    ss += v.x*v.x + v.y*v.y + v.z*v.z + v.w*v.w;
  }
  #pragma unroll
  for (int off = 32; off >= 1; off >>= 1){
    s  += __shfl_down(s, off);
    ss += __shfl_down(ss, off);
  }
  __shared__ float rs[4], rss[4];
  int w = threadIdx.x >> 6;
  if ((threadIdx.x & 63) == 0){ rs[w] = s; rss[w] = ss; }
  __syncthreads();
  if (threadIdx.x == 0){
    s  = rs[0]+rs[1]+rs[2]+rs[3];
    ss = rss[0]+rss[1]+rss[2]+rss[3];
    float m   = s * (1.f/N_);
    float var = ss * (1.f/N_) - m*m;
    float r   = rsqrtf(fmaxf(var, 0.f) + 1e-5f);
    float* dst = (row < 1024) ? (sq + row*2) : (sk + (row-1024)*2);
    dst[0] = m; dst[1] = r;
  }
}

// ---------------- K2: conv1x1 GEMMs (fp32 vector) ----------------
__global__ __launch_bounds__(256) void k_conv(
    const float* __restrict__ q, const float* __restrict__ kk,
    const float* __restrict__ wq, const float* __restrict__ bq,
    const float* __restrict__ wk, const float* __restrict__ bk,
    const float* __restrict__ wsw, const float* __restrict__ bs,
    const float* __restrict__ sq, const float* __restrict__ sk,
    u16* __restrict__ qe, u16* __restrict__ kt,
    u16* __restrict__ se, u16* __restrict__ s2h, u16* __restrict__ s2l)
{
  int spt = blockIdx.x, cot = blockIdx.y, bz = blockIdx.z;
  int b = bz / 3, mode = bz - b*3;
  const float* X; const float* W; const float* bias; const float* st = nullptr;
  if (mode == 0){ X = q  + (size_t)b*C_*N_; W = wq;  bias = bq; st = sq + b*C_*2; }
  else if (mode == 1){ X = kk + (size_t)b*C_*M_; W = wk;  bias = bk; st = sk + b*C_*2; }
  else { X = kk + (size_t)b*C_*M_; W = wsw; bias = bs; }

  __shared__ float Wt[64][17];
  __shared__ float Xt[16][132];
  int tid = threadIdx.x;
  int tco = tid & 15, tsp = tid >> 4;
  int co0 = cot*64, sp0 = spt*128;
  float acc[4][8];
  #pragma unroll
  for (int i=0;i<4;i++)
    #pragma unroll
    for (int j=0;j<8;j++) acc[i][j]=0.f;

  for (int kc = 0; kc < C_; kc += 16){
    { int r = tid >> 2, g = tid & 3;
      float4 wv = *(const float4*)(W + (size_t)(co0+r)*C_ + kc + g*4);
      Wt[r][g*4+0]=wv.x; Wt[r][g*4+1]=wv.y; Wt[r][g*4+2]=wv.z; Wt[r][g*4+3]=wv.w;
    }
    { int r = tid >> 4, cg = (tid & 15)*8;
      const float* xp = X + (size_t)(kc + r)*4096 + sp0 + cg;
      float4 a  = ((const float4*)xp)[0];
      float4 bv = ((const float4*)xp)[1];
      if (mode < 2){
        float mm = st[(kc+r)*2], rr = st[(kc+r)*2+1];
        a.x=(a.x-mm)*rr; a.y=(a.y-mm)*rr; a.z=(a.z-mm)*rr; a.w=(a.w-mm)*rr;
        bv.x=(bv.x-mm)*rr; bv.y=(bv.y-mm)*rr; bv.z=(bv.z-mm)*rr; bv.w=(bv.w-mm)*rr;
      }
      *(float4*)&Xt[r][cg]   = a;
      *(float4*)&Xt[r][cg+4] = bv;
    }
    __syncthreads();
    #pragma unroll
    for (int k2 = 0; k2 < 16; ++k2){
      float a0 = Wt[tco*4+0][k2], a1 = Wt[tco*4+1][k2],
            a2 = Wt[tco*4+2][k2], a3 = Wt[tco*4+3][k2];
      float4 b0 = *(float4*)&Xt[k2][tsp*8];
      float4 b1 = *(float4*)&Xt[k2][tsp*8+4];
      float bb[8] = {b0.x,b0.y,b0.z,b0.w,b1.x,b1.y,b1.z,b1.w};
      #pragma unroll
      for (int j=0;j<8;j++){
        acc[0][j] += a0*bb[j]; acc[1][j] += a1*bb[j];
        acc[2][j] += a2*bb[j]; acc[3][j] += a3*bb[j];
      }
    }
    __syncthreads();
  }
  if (mode == 2){
    #pragma unroll
    for (int i=0;i<4;i++){
      int co = co0 + tco*4 + i;
      float bb = bias[co];
      unsigned pse[4], ph[4], pl[4];
      #pragma unroll
      for (int j=0;j<4;j++){
        unsigned w0=0,w1=0,w2=0;
        #pragma unroll
        for (int e=0;e<2;e++){
          float v = acc[i][2*j+e] + bb;
          u16 hs = f2h(v);
          float vf = h2f(hs);
          float s2 = vf*vf;
          u16 hh = f2h(s2);
          u16 hl = f2h(s2 - h2f(hh));
          w0 |= ((unsigned)hs) << (16*e);
          w1 |= ((unsigned)hh) << (16*e);
          w2 |= ((unsigned)hl) << (16*e);
        }
        pse[j]=w0; ph[j]=w1; pl[j]=w2;
      }
      size_t base = ((size_t)(b*C_) + co)*M_ + sp0 + tsp*8;
      *(uint4*)(se  + base) = make_uint4(pse[0],pse[1],pse[2],pse[3]);
      *(uint4*)(s2h + base) = make_uint4(ph[0],ph[1],ph[2],ph[3]);
      *(uint4*)(s2l + base) = make_uint4(pl[0],pl[1],pl[2],pl[3]);
    }
  } else {
    u16* o = (mode==0) ? qe : kt;
    float sc = (mode==0) ? LOG2E : 1.f;
    float bb4[4];
    #pragma unroll
    for (int i=0;i<4;i++) bb4[i] = bias[co0 + tco*4 + i];
    #pragma unroll
    for (int j=0;j<8;j++){
      int sp = sp0 + tsp*8 + j;
      unsigned h01 = (unsigned)f2h((acc[0][j]+bb4[0])*sc)
                   | (((unsigned)f2h((acc[1][j]+bb4[1])*sc))<<16);
      unsigned h23 = (unsigned)f2h((acc[2][j]+bb4[2])*sc)
                   | (((unsigned)f2h((acc[3][j]+bb4[3])*sc))<<16);
      *(uint2*)(o + ((size_t)b*4096 + sp)*C_ + co0 + tco*4) = make_uint2(h01, h23);
    }
  }
}

// ---------------- K3: swapped-QK flash attention + AdaAttN epilogue ----------------
// 256 thr (4 waves), QB=64 q-rows/block, kv-tile 32, grid (64,4)=256 blocks.
// Wave w: QK rows [w*16, w*16+16) (in-register softmax), PV cols [w*64, w*64+64).
// LDS swizzles: KT chunk16 ^ (row&7); SE/S2H/S2L chunk16 ^ ((c>>1)&3);
// WT chunk16 ^ ((row>>1)&3). All verified 2-lane/bank-slot per quarter-wave.
__global__ __launch_bounds__(256, 1) void k_attn(
    const float* __restrict__ q, const float* __restrict__ stq,
    const u16* __restrict__ qe_g, const u16* __restrict__ kt_g,
    const u16* __restrict__ se_g, const u16* __restrict__ s2h_g,
    const u16* __restrict__ s2l_g, float* __restrict__ out)
{
  __shared__ u16 KTs[2][KVB*256];     // 16KB x2
  __shared__ u16 SEs[2][C_*KVB];      // 16KB x2
  __shared__ u16 S2Hs[2][C_*KVB];
  __shared__ u16 S2Ls[2][C_*KVB];
  __shared__ unsigned WTw[QB*16];     // P weights f16, 64 rows x 64B
  __shared__ float SRES[QB];
  __shared__ float LRUNS[QB];
  __shared__ int FLG[4];

  const int tid = threadIdx.x;
  const int wid = tid >> 6, lane = tid & 63;
  const int l15 = lane & 15, lg = lane >> 4;
  const int b = blockIdx.y;
  const int n0 = blockIdx.x * QB;

  // Q fragments for this wave's 16 rows (B-operand: lane l15 = q-row col)
  half8 qf[8];
  {
    const u16* qb = qe_g + ((size_t)(b*N_ + n0 + wid*16 + l15))*C_;
    #pragma unroll
    for (int ks=0; ks<8; ++ks) qf[ks] = *(const half8*)(qb + ks*32 + lg*8);
  }

  // staging source byte-offsets (pre-swizzled so linear LDS dst = swizzled layout)
  int ktsrc[4], sesrc[4];
  #pragma unroll
  for (int i=0;i<4;i++){
    int g = (i*4 + wid)*64 + lane;
    int row = g >> 5, cin = g & 31;
    ktsrc[i] = row*512 + ((cin ^ (row & 7)) << 4);
    int c = g >> 2, mch = (g & 3) ^ ((c >> 1) & 3);
    sesrc[i] = c*8192 + mch*16;
  }
  const char* ktg = (const char*)kt_g  + (size_t)b*M_*512;
  const char* seg = (const char*)se_g  + (size_t)b*C_*M_*2;
  const char* shg = (const char*)s2h_g + (size_t)b*C_*M_*2;
  const char* slg = (const char*)s2l_g + (size_t)b*C_*M_*2;

  float m_run = -1e30f, lrun = 0.f;
  f32x4 accm[4][4], accs[4][4];
  #pragma unroll
  for (int i=0;i<4;i++)
    #pragma unroll
    for (int j=0;j<4;j++){ accm[i][j] = (f32x4)(0.f); accs[i][j] = (f32x4)(0.f); }

  // prologue: stage tile 0 into buf 0
  #pragma unroll
  for (int i=0;i<4;i++){
    int o = (i*4 + wid)*1024;
    gll16(ktg + ktsrc[i], (char*)&KTs[0][0] + o);
    gll16(seg + sesrc[i], (char*)&SEs[0][0] + o);
    gll16(shg + sesrc[i], (char*)&S2Hs[0][0] + o);
    gll16(slg + sesrc[i], (char*)&S2Ls[0][0] + o);
  }

  for (int t=0; t<M_/KVB; ++t){
    const int buf = t & 1;
    __syncthreads();                      // B1: stage(t) done (drains vmcnt), prev PV done

    // prefetch next tile into other buffer (all waves past PV(t-1) at B1)
    if (t+1 < M_/KVB){
      const int nb = buf ^ 1;
      int koff = (t+1)*(KVB*512);
      int soff = (t+1)*(KVB*2);
      #pragma unroll
      for (int i=0;i<4;i++){
        int o = (i*4 + wid)*1024;
        gll16(ktg + koff + ktsrc[i], (char*)&KTs[nb][0] + o);
        gll16(seg + soff + sesrc[i], (char*)&SEs[nb][0] + o);
        gll16(shg + soff + sesrc[i], (char*)&S2Hs[nb][0] + o);
        gll16(slg + soff + sesrc[i], (char*)&S2Ls[nb][0] + o);
      }
    }

    // ---- QK^T swapped: D[m][n], lane holds n=l15, m = lg*4+r (+16) ----
    f32x4 L0 = (f32x4)(0.f), L1 = (f32x4)(0.f);
    {
      const char* ktb = (const char*)&KTs[buf][0];
      #pragma unroll
      for (int ks=0; ks<8; ++ks){
        int ch = ((ks*4 + lg) ^ (l15 & 7)) << 4;
        half8 a0 = *(const half8*)(ktb + l15*512 + ch);
        half8 a1 = *(const half8*)(ktb + (16+l15)*512 + ch);
        L0 = __builtin_amdgcn_mfma_f32_16x16x32_f16(a0, qf[ks], L0, 0,0,0);
        L1 = __builtin_amdgcn_mfma_f32_16x16x32_f16(a1, qf[ks], L1, 0,0,0);
      }
    }
    // ---- in-register online softmax for row l15 ----
    float p[8] = {L0[0],L0[1],L0[2],L0[3],L1[0],L1[1],L1[2],L1[3]};
    float pm = p[0];
    #pragma unroll
    for (int j=1;j<8;j++) pm = fmaxf(pm, p[j]);
    pm = fmaxf(pm, __shfl_xor(pm, 16));
    pm = fmaxf(pm, __shfl_xor(pm, 32));
    int flag = __any(pm > m_run + 8.0f);  // defer-max THR=8 (exp2 domain)
    float sv = 1.0f;
    if (flag){
      float mn = fmaxf(m_run, pm);
      sv = exp2f(m_run - mn);
      m_run = mn;
      lrun *= sv;
    }
    if (lg == 0) SRES[wid*16 + l15] = sv;
    if (lane == 0) FLG[wid] = flag;
    unsigned W0 = pkrtz(exp2f(p[0]-m_run), exp2f(p[1]-m_run));
    unsigned W1 = pkrtz(exp2f(p[2]-m_run), exp2f(p[3]-m_run));
    unsigned W2 = pkrtz(exp2f(p[4]-m_run), exp2f(p[5]-m_run));
    unsigned W3 = pkrtz(exp2f(p[6]-m_run), exp2f(p[7]-m_run));
    {
      int row = wid*16 + l15;
      int swz = (l15 >> 1) & 3;
      char* wb = (char*)WTw + row*64 + ((lg & 1) << 3);
      *(uint2*)(wb + ((((lg>>1)    ) ^ swz) << 4)) = make_uint2(W0, W1);
      *(uint2*)(wb + (((2 + (lg>>1)) ^ swz) << 4)) = make_uint2(W2, W3);
    }
    float rs = sum2(W0) + sum2(W1) + sum2(W2) + sum2(W3);  // ROUNDED row-sum
    rs += __shfl_xor(rs, 16);
    rs += __shfl_xor(rs, 32);
    lrun += rs;
    __syncthreads();                      // B2: WT/SRES/FLG ready

    // conditional accumulator rescale (rare after warm-up)
    int bf = FLG[0] | FLG[1] | FLG[2] | FLG[3];
    if (bf){
      #pragma unroll
      for (int rt=0;rt<4;rt++){
        f32x4 s4 = *(const f32x4*)&SRES[rt*16 + lg*4];
        #pragma unroll
        for (int ct=0;ct<4;ct++){
          #pragma unroll
          for (int r=0;r<4;r++){ accm[rt][ct][r] *= s4[r]; accs[rt][ct][r] *= s4[r]; }
        }
      }
    }

    // ---- PV: mean += P*se ; E[s^2] += P*s2h + P*s2l ----
    {
      half8 a[4];
      #pragma unroll
      for (int rt=0;rt<4;rt++){
        int row = rt*16 + l15;
        a[rt] = *(const half8*)((char*)WTw + row*64 + ((lg ^ ((l15>>1)&3)) << 4));
      }
      const char* seb = (const char*)&SEs[buf][0];
      const char* shb = (const char*)&S2Hs[buf][0];
      const char* slb = (const char*)&S2Ls[buf][0];
      #pragma unroll
      for (int ct=0;ct<4;ct++){
        int c = wid*64 + ct*16 + l15;
        int co = c*64 + ((lg ^ ((c>>1)&3)) << 4);
        half8 v  = *(const half8*)(seb + co);
        half8 h2 = *(const half8*)(shb + co);
        half8 l2 = *(const half8*)(slb + co);
        #pragma unroll
        for (int rt=0;rt<4;rt++){
          accm[rt][ct] = __builtin_amdgcn_mfma_f32_16x16x32_f16(a[rt], v,  accm[rt][ct], 0,0,0);
          accs[rt][ct] = __builtin_amdgcn_mfma_f32_16x16x32_f16(a[rt], h2, accs[rt][ct], 0,0,0);
          accs[rt][ct] = __builtin_amdgcn_mfma_f32_16x16x32_f16(a[rt], l2, accs[rt][ct], 0,0,0);
        }
      }
    }
  }

  if (lg == 0) LRUNS[wid*16 + l15] = lrun;
  __syncthreads();

  // ---- epilogue: normalize, var=relu(E[s^2]-mean^2), cs = qnorm*std + mean ----
  #pragma unroll
  for (int rt=0;rt<4;rt++){
    f32x4 lv = *(const f32x4*)&LRUNS[rt*16 + lg*4];
    f32x4 inv;
    #pragma unroll
    for (int r=0;r<4;r++) inv[r] = 1.f / lv[r];
    #pragma unroll
    for (int ct=0;ct<4;ct++){
      int c = wid*64 + ct*16 + l15;
      float2 st = *(const float2*)(stq + (size_t)(b*C_ + c)*2);
      size_t base = ((size_t)(b*C_ + c))*(size_t)N_ + (size_t)(n0 + rt*16 + lg*4);
      f32x4 qv = *(const f32x4*)(q + base);
      f32x4 res;
      #pragma unroll
      for (int r=0;r<4;r++){
        float mean = accm[rt][ct][r] * inv[r];
        float ms   = accs[rt][ct][r] * inv[r];
        float sd   = sqrtf(fmaxf(ms - mean*mean, 0.f));
        float qn   = (qv[r] - st.x) * st.y;
        res[r] = qn * sd + mean;
      }
      *(f32x4*)(out + base) = res;
    }
  }
}

extern "C" void kernel_launch(void* const* d_in, const int* in_sizes, int n_in,
                              void* d_out, int out_size, void* d_ws, size_t ws_size,
                              hipStream_t stream){
  const float* q   = (const float*)d_in[0];
  const float* k   = (const float*)d_in[1];
  const float* wq  = (const float*)d_in[2];
  const float* bq  = (const float*)d_in[3];
  const float* wk  = (const float*)d_in[4];
  const float* bk  = (const float*)d_in[5];
  const float* wsw = (const float*)d_in[6];
  const float* bs  = (const float*)d_in[7];
  float* out = (float*)d_out;

  char* w = (char*)d_ws;
  float* stq = (float*)w;                       // B*C*2 f32 = 8 KB
  float* stk = (float*)(w + 8192);
  u16* qe  = (u16*)(w + 16384);                 // each B*4096*256 f16 = 8 MB
  u16* kt  = qe  + (size_t)B_*N_*C_;
  u16* se  = kt  + (size_t)B_*M_*C_;
  u16* s2h = se  + (size_t)B_*M_*C_;
  u16* s2l = s2h + (size_t)B_*M_*C_;

  k_stats<<<dim3(2048), dim3(256), 0, stream>>>(q, k, stq, stk);
  k_conv<<<dim3(32, 4, 12), dim3(256), 0, stream>>>(q, k, wq, bq, wk, bk, wsw, bs,
                                                    stq, stk, qe, kt, se, s2h, s2l);
  k_attn<<<dim3(N_/QB, B_), dim3(256), 0, stream>>>(q, stq, qe, kt, se, s2h, s2l, out);
}

// Round 6
// 318.266 us; speedup vs baseline: 1.8813x; 1.3236x over previous
//
#include <hip/hip_runtime.h>
#include <hip/hip_bf16.h>
#include <cstdint>

typedef unsigned short u16;
typedef __attribute__((ext_vector_type(8))) _Float16 half8;  // 8 f16 in 4 VGPRs
typedef __attribute__((ext_vector_type(2))) __fp16 fp16x2;
typedef __attribute__((ext_vector_type(4))) float f32x4;

#define B_ 4
#define C_ 256
#define N_ 4096
#define M_ 4096
#define QB 32
#define KVB 32
#define LOG2E 1.44269504088896340736f

__device__ __forceinline__ u16 f2h(float x){
  _Float16 h = (_Float16)x;
  return __builtin_bit_cast(u16, h);
}
__device__ __forceinline__ float h2f(u16 h){
  return (float)__builtin_bit_cast(_Float16, h);
}
__device__ __forceinline__ unsigned pkrtz(float a, float b){
  fp16x2 h = __builtin_amdgcn_cvt_pkrtz(a, b);
  return __builtin_bit_cast(unsigned, h);
}
__device__ __forceinline__ float sum2(unsigned w){
  fp16x2 h = __builtin_bit_cast(fp16x2, w);
  return (float)h.x + (float)h.y;
}
__device__ __forceinline__ void gll16(const void* gsrc, void* ldst){
  __builtin_amdgcn_global_load_lds(
      (const __attribute__((address_space(1))) unsigned int*)gsrc,
      (__attribute__((address_space(3))) unsigned int*)ldst, 16, 0, 0);
}
// LDS-only barrier: does NOT drain vmcnt -> prefetch global_load_lds stays in flight
__device__ __forceinline__ void bar_lds(){
  asm volatile("s_waitcnt lgkmcnt(0)" ::: "memory");
  __builtin_amdgcn_s_barrier();
}

// ---------------- K1: instance-norm stats (mean, rstd) per (b,c) ----------------
__global__ __launch_bounds__(256) void k_stats(const float* __restrict__ q,
                                               const float* __restrict__ k,
                                               float* __restrict__ sq,
                                               float* __restrict__ sk){
  int row = blockIdx.x;            // 0..2047 : first 1024 are q rows, then k rows
  const float* src = (row < 1024) ? (q + (size_t)row * N_)
                                  : (k + (size_t)(row - 1024) * N_);
  float s = 0.f, ss = 0.f;
  for (int i = threadIdx.x; i < N_/4; i += 256){
    float4 v = ((const float4*)src)[i];
    s  += v.x + v.y + v.z + v.w;
    ss += v.x*v.x + v.y*v.y + v.z*v.z + v.w*v.w;
  }
  #pragma unroll
  for (int off = 32; off >= 1; off >>= 1){
    s  += __shfl_down(s, off);
    ss += __shfl_down(ss, off);
  }
  __shared__ float rs[4], rss[4];
  int w = threadIdx.x >> 6;
  if ((threadIdx.x & 63) == 0){ rs[w] = s; rss[w] = ss; }
  __syncthreads();
  if (threadIdx.x == 0){
    s  = rs[0]+rs[1]+rs[2]+rs[3];
    ss = rss[0]+rss[1]+rss[2]+rss[3];
    float m   = s * (1.f/N_);
    float var = ss * (1.f/N_) - m*m;
    float r   = rsqrtf(fmaxf(var, 0.f) + 1e-5f);
    float* dst = (row < 1024) ? (sq + row*2) : (sk + (row-1024)*2);
    dst[0] = m; dst[1] = r;
  }
}

// ---------------- K2: conv1x1 GEMMs (fp32 vector) ----------------
__global__ __launch_bounds__(256) void k_conv(
    const float* __restrict__ q, const float* __restrict__ kk,
    const float* __restrict__ wq, const float* __restrict__ bq,
    const float* __restrict__ wk, const float* __restrict__ bk,
    const float* __restrict__ wsw, const float* __restrict__ bs,
    const float* __restrict__ sq, const float* __restrict__ sk,
    u16* __restrict__ qe, u16* __restrict__ kt, u16* __restrict__ se)
{
  int spt = blockIdx.x, cot = blockIdx.y, bz = blockIdx.z;
  int b = bz / 3, mode = bz - b*3;
  const float* X; const float* W; const float* bias; const float* st = nullptr;
  if (mode == 0){ X = q  + (size_t)b*C_*N_; W = wq;  bias = bq; st = sq + b*C_*2; }
  else if (mode == 1){ X = kk + (size_t)b*C_*M_; W = wk;  bias = bk; st = sk + b*C_*2; }
  else { X = kk + (size_t)b*C_*M_; W = wsw; bias = bs; }

  __shared__ float Wt[64][17];
  __shared__ float Xt[16][132];
  int tid = threadIdx.x;
  int tco = tid & 15, tsp = tid >> 4;
  int co0 = cot*64, sp0 = spt*128;
  float acc[4][8];
  #pragma unroll
  for (int i=0;i<4;i++)
    #pragma unroll
    for (int j=0;j<8;j++) acc[i][j]=0.f;

  for (int kc = 0; kc < C_; kc += 16){
    { int r = tid >> 2, g = tid & 3;
      float4 wv = *(const float4*)(W + (size_t)(co0+r)*C_ + kc + g*4);
      Wt[r][g*4+0]=wv.x; Wt[r][g*4+1]=wv.y; Wt[r][g*4+2]=wv.z; Wt[r][g*4+3]=wv.w;
    }
    { int r = tid >> 4, cg = (tid & 15)*8;
      const float* xp = X + (size_t)(kc + r)*4096 + sp0 + cg;
      float4 a  = ((const float4*)xp)[0];
      float4 bv = ((const float4*)xp)[1];
      if (mode < 2){
        float mm = st[(kc+r)*2], rr = st[(kc+r)*2+1];
        a.x=(a.x-mm)*rr; a.y=(a.y-mm)*rr; a.z=(a.z-mm)*rr; a.w=(a.w-mm)*rr;
        bv.x=(bv.x-mm)*rr; bv.y=(bv.y-mm)*rr; bv.z=(bv.z-mm)*rr; bv.w=(bv.w-mm)*rr;
      }
      *(float4*)&Xt[r][cg]   = a;
      *(float4*)&Xt[r][cg+4] = bv;
    }
    __syncthreads();
    #pragma unroll
    for (int k2 = 0; k2 < 16; ++k2){
      float a0 = Wt[tco*4+0][k2], a1 = Wt[tco*4+1][k2],
            a2 = Wt[tco*4+2][k2], a3 = Wt[tco*4+3][k2];
      float4 b0 = *(float4*)&Xt[k2][tsp*8];
      float4 b1 = *(float4*)&Xt[k2][tsp*8+4];
      float bb[8] = {b0.x,b0.y,b0.z,b0.w,b1.x,b1.y,b1.z,b1.w};
      #pragma unroll
      for (int j=0;j<8;j++){
        acc[0][j] += a0*bb[j]; acc[1][j] += a1*bb[j];
        acc[2][j] += a2*bb[j]; acc[3][j] += a3*bb[j];
      }
    }
    __syncthreads();
  }
  if (mode == 2){
    #pragma unroll
    for (int i=0;i<4;i++){
      int co = co0 + tco*4 + i;
      float bb = bias[co];
      unsigned pse[4];
      #pragma unroll
      for (int j=0;j<4;j++){
        pse[j] = (unsigned)f2h(acc[i][2*j] + bb)
               | (((unsigned)f2h(acc[i][2*j+1] + bb)) << 16);
      }
      size_t base = ((size_t)(b*C_) + co)*M_ + sp0 + tsp*8;
      *(uint4*)(se + base) = make_uint4(pse[0],pse[1],pse[2],pse[3]);
    }
  } else {
    u16* o = (mode==0) ? qe : kt;
    float sc = (mode==0) ? LOG2E : 1.f;
    float bb4[4];
    #pragma unroll
    for (int i=0;i<4;i++) bb4[i] = bias[co0 + tco*4 + i];
    #pragma unroll
    for (int j=0;j<8;j++){
      int sp = sp0 + tsp*8 + j;
      unsigned h01 = (unsigned)f2h((acc[0][j]+bb4[0])*sc)
                   | (((unsigned)f2h((acc[1][j]+bb4[1])*sc))<<16);
      unsigned h23 = (unsigned)f2h((acc[2][j]+bb4[2])*sc)
                   | (((unsigned)f2h((acc[3][j]+bb4[3])*sc))<<16);
      *(uint2*)(o + ((size_t)b*4096 + sp)*C_ + co0 + tco*4) = make_uint2(h01, h23);
    }
  }
}

// ---------------- K3: swapped-QK flash attention + AdaAttN epilogue ----------------
// 256 thr (4 waves), QB=32 q-rows/block, kv-tile 32, grid (128,4)=512 blocks (2/CU).
// QK: wave (qg=wid&1, mh=wid>>1) computes scores of q-rows qg*16..+16 vs m-rows mh*16..+16.
// PV: wave wid handles c-cols wid*64..+64 for all 32 q-rows; s^2 hi/lo computed in-register.
__global__ __launch_bounds__(256, 2) void k_attn(
    const float* __restrict__ q, const float* __restrict__ stq,
    const u16* __restrict__ qe_g, const u16* __restrict__ kt_g,
    const u16* __restrict__ se_g, float* __restrict__ out)
{
  __shared__ u16 KTs[2][KVB*256];     // 16KB x2, chunk16 ^ (row&7)
  __shared__ u16 SEs[2][C_*KVB];      // 16KB x2, chunk16 ^ ((c>>1)&3)
  __shared__ unsigned WTw[QB*16];     // P weights f16, 32 rows x 64B, chunk16 ^ ((row>>1)&3)
  __shared__ float PMX[4][16];
  __shared__ float SRES[QB];
  __shared__ float LRUNS[2][QB];
  __shared__ int FLG[2];

  const int tid = threadIdx.x;
  const int wid = tid >> 6, lane = tid & 63;
  const int l15 = lane & 15, lg = lane >> 4;
  const int qg = wid & 1, mh = wid >> 1;
  const int b = blockIdx.y;
  const int n0 = blockIdx.x * QB;

  // Q fragments: this wave's QK q-rows are qg*16 + l15 (B-operand cols)
  half8 qf[8];
  {
    const u16* qb = qe_g + ((size_t)(b*N_ + n0 + qg*16 + l15))*C_;
    #pragma unroll
    for (int ks=0; ks<8; ++ks) qf[ks] = *(const half8*)(qb + ks*32 + lg*8);
  }

  // staging source byte-offsets (pre-swizzled so linear LDS dst = swizzled layout)
  int ktsrc[4], sesrc[4];
  #pragma unroll
  for (int i=0;i<4;i++){
    int g = (i*4 + wid)*64 + lane;
    int row = g >> 5, cin = g & 31;
    ktsrc[i] = row*512 + ((cin ^ (row & 7)) << 4);
    int c = g >> 2, mch = (g & 3) ^ ((c >> 1) & 3);
    sesrc[i] = c*8192 + mch*16;
  }
  const char* ktg = (const char*)kt_g + (size_t)b*M_*512;
  const char* seg = (const char*)se_g + (size_t)b*C_*M_*2;

  float m_run = -1e30f, lrun = 0.f;
  f32x4 accm[2][4], accs[2][4];
  #pragma unroll
  for (int i=0;i<2;i++)
    #pragma unroll
    for (int j=0;j<4;j++){ accm[i][j] = (f32x4)(0.f); accs[i][j] = (f32x4)(0.f); }

  // prologue: stage tile 0 into buf 0
  #pragma unroll
  for (int i=0;i<4;i++){
    int o = (i*4 + wid)*1024;
    gll16(ktg + ktsrc[i], (char*)&KTs[0][0] + o);
    gll16(seg + sesrc[i], (char*)&SEs[0][0] + o);
  }

  for (int t=0; t<M_/KVB; ++t){
    const int buf = t & 1;
    __syncthreads();     // B1: full drain (stage(t) complete for ALL waves), prev PV done

    // prefetch next tile; stays in flight across the raw barriers below
    if (t+1 < M_/KVB){
      const int nb = buf ^ 1;
      int koff = (t+1)*(KVB*512);
      int soff = (t+1)*(KVB*2);
      #pragma unroll
      for (int i=0;i<4;i++){
        int o = (i*4 + wid)*1024;
        gll16(ktg + koff + ktsrc[i], (char*)&KTs[nb][0] + o);
        gll16(seg + soff + sesrc[i], (char*)&SEs[nb][0] + o);
      }
    }

    // ---- QK^T swapped: D[m][q], lane holds q=l15, m = mh*16 + lg*4 + r ----
    f32x4 L0 = (f32x4)(0.f);
    {
      const char* ktb = (const char*)&KTs[buf][0];
      int krow = mh*16 + l15;
      #pragma unroll
      for (int ks=0; ks<8; ++ks){
        half8 a0 = *(const half8*)(ktb + krow*512 + (((ks*4 + lg) ^ (l15 & 7)) << 4));
        L0 = __builtin_amdgcn_mfma_f32_16x16x32_f16(a0, qf[ks], L0, 0,0,0);
      }
    }
    // ---- partial row-max over this wave's 16 m ----
    float pm = fmaxf(fmaxf(L0[0], L0[1]), fmaxf(L0[2], L0[3]));
    pm = fmaxf(pm, __shfl_xor(pm, 16));
    pm = fmaxf(pm, __shfl_xor(pm, 32));
    if (lg == 0) PMX[wid][l15] = pm;
    bar_lds();           // Bmax: exchange partial maxes (no vmcnt drain)

    float m_tile = fmaxf(pm, PMX[wid ^ 2][l15]);
    int flag = __any(m_tile > m_run + 8.0f);   // defer-max THR=8 (exp2 domain)
    float sv = 1.0f;
    if (flag){
      float mn = fmaxf(m_run, m_tile);
      sv = exp2f(m_run - mn);
      m_run = mn;
    }
    if (mh == 0 && lg == 0) SRES[qg*16 + l15] = sv;
    if (mh == 0 && lane == 0) FLG[qg] = flag;
    unsigned W0 = pkrtz(exp2f(L0[0]-m_run), exp2f(L0[1]-m_run));
    unsigned W1 = pkrtz(exp2f(L0[2]-m_run), exp2f(L0[3]-m_run));
    {
      int row = qg*16 + l15;
      int c16 = (mh*2 + (lg >> 1)) ^ ((l15 >> 1) & 3);
      *(uint2*)((char*)WTw + row*64 + (c16 << 4) + ((lg & 1) << 3)) = make_uint2(W0, W1);
    }
    float rs = sum2(W0) + sum2(W1);            // ROUNDED partial row-sum (this mh)
    rs += __shfl_xor(rs, 16);
    rs += __shfl_xor(rs, 32);
    lrun = lrun * sv + rs;
    bar_lds();           // B2: WT/SRES/FLG ready (no vmcnt drain)

    // conditional accumulator rescale (rare after warm-up)
    if (FLG[0] | FLG[1]){
      #pragma unroll
      for (int rt=0;rt<2;rt++){
        f32x4 s4 = *(const f32x4*)&SRES[rt*16 + lg*4];
        #pragma unroll
        for (int ct=0;ct<4;ct++){
          #pragma unroll
          for (int r=0;r<4;r++){ accm[rt][ct][r] *= s4[r]; accs[rt][ct][r] *= s4[r]; }
        }
      }
    }

    // ---- PV: mean += P*se ; E[s^2] += P*h2 + P*l2 (s^2 hi/lo in-register) ----
    {
      half8 a[2];
      #pragma unroll
      for (int rt=0;rt<2;rt++){
        int row = rt*16 + l15;
        a[rt] = *(const half8*)((char*)WTw + row*64 + ((lg ^ ((l15>>1)&3)) << 4));
      }
      const char* seb = (const char*)&SEs[buf][0];
      #pragma unroll
      for (int ct=0;ct<4;ct++){
        int c = wid*64 + ct*16 + l15;
        half8 v = *(const half8*)(seb + c*64 + ((lg ^ ((c>>1)&3)) << 4));
        half8 h2 = v * v;                                   // v_pk_mul_f16
        half8 l2;
#if __has_builtin(__builtin_elementwise_fma)
        l2 = __builtin_elementwise_fma(v, v, -h2);          // exact residual, fits f16
#else
        #pragma unroll
        for (int e=0;e<8;e++){ float vf=(float)v[e]; l2[e]=(_Float16)(vf*vf-(float)h2[e]); }
#endif
        #pragma unroll
        for (int rt=0;rt<2;rt++){
          accm[rt][ct] = __builtin_amdgcn_mfma_f32_16x16x32_f16(a[rt], v,  accm[rt][ct], 0,0,0);
          accs[rt][ct] = __builtin_amdgcn_mfma_f32_16x16x32_f16(a[rt], h2, accs[rt][ct], 0,0,0);
          accs[rt][ct] = __builtin_amdgcn_mfma_f32_16x16x32_f16(a[rt], l2, accs[rt][ct], 0,0,0);
        }
      }
    }
  }

  if (lg == 0) LRUNS[mh][qg*16 + l15] = lrun;
  __syncthreads();

  // ---- epilogue: combine l, normalize, var=relu(E[s^2]-mean^2), cs = qn*std + mean ----
  #pragma unroll
  for (int rt=0;rt<2;rt++){
    f32x4 lv0 = *(const f32x4*)&LRUNS[0][rt*16 + lg*4];
    f32x4 lv1 = *(const f32x4*)&LRUNS[1][rt*16 + lg*4];
    f32x4 inv;
    #pragma unroll
    for (int r=0;r<4;r++) inv[r] = 1.f / (lv0[r] + lv1[r]);
    #pragma unroll
    for (int ct=0;ct<4;ct++){
      int c = wid*64 + ct*16 + l15;
      float2 st = *(const float2*)(stq + (size_t)(b*C_ + c)*2);
      size_t base = ((size_t)(b*C_ + c))*(size_t)N_ + (size_t)(n0 + rt*16 + lg*4);
      f32x4 qv = *(const f32x4*)(q + base);
      f32x4 res;
      #pragma unroll
      for (int r=0;r<4;r++){
        float mean = accm[rt][ct][r] * inv[r];
        float ms   = accs[rt][ct][r] * inv[r];
        float sd   = sqrtf(fmaxf(ms - mean*mean, 0.f));
        float qn   = (qv[r] - st.x) * st.y;
        res[r] = qn * sd + mean;
      }
      *(f32x4*)(out + base) = res;
    }
  }
}

extern "C" void kernel_launch(void* const* d_in, const int* in_sizes, int n_in,
                              void* d_out, int out_size, void* d_ws, size_t ws_size,
                              hipStream_t stream){
  const float* q   = (const float*)d_in[0];
  const float* k   = (const float*)d_in[1];
  const float* wq  = (const float*)d_in[2];
  const float* bq  = (const float*)d_in[3];
  const float* wk  = (const float*)d_in[4];
  const float* bk  = (const float*)d_in[5];
  const float* wsw = (const float*)d_in[6];
  const float* bs  = (const float*)d_in[7];
  float* out = (float*)d_out;

  char* w = (char*)d_ws;
  float* stq = (float*)w;                       // B*C*2 f32 = 8 KB
  float* stk = (float*)(w + 8192);
  u16* qe  = (u16*)(w + 16384);                 // each B*4096*256 f16 = 8 MB
  u16* kt  = qe  + (size_t)B_*N_*C_;
  u16* se  = kt  + (size_t)B_*M_*C_;

  k_stats<<<dim3(2048), dim3(256), 0, stream>>>(q, k, stq, stk);
  k_conv<<<dim3(32, 4, 12), dim3(256), 0, stream>>>(q, k, wq, bq, wk, bk, wsw, bs,
                                                    stq, stk, qe, kt, se);
  k_attn<<<dim3(N_/QB, B_), dim3(256), 0, stream>>>(q, stq, qe, kt, se, out);
}

// Round 7
// 252.471 us; speedup vs baseline: 2.3716x; 1.2606x over previous
//
#include <hip/hip_runtime.h>
#include <hip/hip_bf16.h>
#include <cstdint>

typedef unsigned short u16;
typedef __attribute__((ext_vector_type(8))) _Float16 half8;  // 8 f16 in 4 VGPRs
typedef __attribute__((ext_vector_type(2))) __fp16 fp16x2;
typedef __attribute__((ext_vector_type(4))) float f32x4;

#define B_ 4
#define C_ 256
#define N_ 4096
#define M_ 4096
#define QB 32
#define KVB 32
#define LOG2E 1.44269504088896340736f

__device__ __forceinline__ u16 f2h(float x){
  _Float16 h = (_Float16)x;
  return __builtin_bit_cast(u16, h);
}
__device__ __forceinline__ float h2f(u16 h){
  return (float)__builtin_bit_cast(_Float16, h);
}
__device__ __forceinline__ unsigned pkrtz(float a, float b){
  fp16x2 h = __builtin_amdgcn_cvt_pkrtz(a, b);
  return __builtin_bit_cast(unsigned, h);
}
__device__ __forceinline__ float sum2(unsigned w){
  fp16x2 h = __builtin_bit_cast(fp16x2, w);
  return (float)h.x + (float)h.y;
}
__device__ __forceinline__ void gll16(const void* gsrc, void* ldst){
  __builtin_amdgcn_global_load_lds(
      (const __attribute__((address_space(1))) unsigned int*)gsrc,
      (__attribute__((address_space(3))) unsigned int*)ldst, 16, 0, 0);
}
// LDS-only barrier: does NOT drain vmcnt -> prefetch global_load_lds stays in flight
__device__ __forceinline__ void bar_lds(){
  asm volatile("s_waitcnt lgkmcnt(0)" ::: "memory");
  __builtin_amdgcn_s_barrier();
}

// ---------------- K1: instance-norm stats (mean, rstd) per (b,c) ----------------
__global__ __launch_bounds__(256) void k_stats(const float* __restrict__ q,
                                               const float* __restrict__ k,
                                               float* __restrict__ sq,
                                               float* __restrict__ sk){
  int row = blockIdx.x;            // 0..2047 : first 1024 are q rows, then k rows
  const float* src = (row < 1024) ? (q + (size_t)row * N_)
                                  : (k + (size_t)(row - 1024) * N_);
  float s = 0.f, ss = 0.f;
  for (int i = threadIdx.x; i < N_/4; i += 256){
    float4 v = ((const float4*)src)[i];
    s  += v.x + v.y + v.z + v.w;
    ss += v.x*v.x + v.y*v.y + v.z*v.z + v.w*v.w;
  }
  #pragma unroll
  for (int off = 32; off >= 1; off >>= 1){
    s  += __shfl_down(s, off);
    ss += __shfl_down(ss, off);
  }
  __shared__ float rs[4], rss[4];
  int w = threadIdx.x >> 6;
  if ((threadIdx.x & 63) == 0){ rs[w] = s; rss[w] = ss; }
  __syncthreads();
  if (threadIdx.x == 0){
    s  = rs[0]+rs[1]+rs[2]+rs[3];
    ss = rss[0]+rss[1]+rss[2]+rss[3];
    float m   = s * (1.f/N_);
    float var = ss * (1.f/N_) - m*m;
    float r   = rsqrtf(fmaxf(var, 0.f) + 1e-5f);
    float* dst = (row < 1024) ? (sq + row*2) : (sk + (row-1024)*2);
    dst[0] = m; dst[1] = r;
  }
}

// ---------------- K1b: fold inorm into weights; f16 hi/lo, frag-major layout ----
// z 0-3: Wq'*rq[b]*LOG2E (b=z); z 4-7: Wk'*rk[b]; z 8: Ws.
// layout: wh/wl u16 index = ((z*8 + ks)*256 + co)*32 + lg*8 + e  (ks=kc>>5, lg=(kc>>3)&3, e=kc&7)
__global__ __launch_bounds__(64) void k_wprep(
    const float* __restrict__ wq, const float* __restrict__ bq,
    const float* __restrict__ wk, const float* __restrict__ bk,
    const float* __restrict__ wsw, const float* __restrict__ bs,
    const float* __restrict__ sq, const float* __restrict__ sk,
    u16* __restrict__ wh, u16* __restrict__ wl, float* __restrict__ bias2)
{
  int co = blockIdx.x, z = blockIdx.y;
  int lane = threadIdx.x;
  const float* W; const float* bias; const float* st = nullptr; float sc = 1.f;
  if (z < 4){ W = wq; bias = bq; st = sq + z*512; sc = LOG2E; }
  else if (z < 8){ W = wk; bias = bk; st = sk + (z-4)*512; }
  else { W = wsw; bias = bs; }
  float4 wv = *(const float4*)(W + co*256 + lane*4);
  float w4[4] = {wv.x, wv.y, wv.z, wv.w};
  float vs[4];
  float bsum = 0.f;
  if (st){
    float4 s0 = *(const float4*)(st + lane*8);      // m0 r0 m1 r1
    float4 s1 = *(const float4*)(st + lane*8 + 4);  // m2 r2 m3 r3
    float mm[4] = {s0.x, s0.z, s1.x, s1.z};
    float rr[4] = {s0.y, s0.w, s1.y, s1.w};
    #pragma unroll
    for (int i=0;i<4;i++){
      vs[i] = w4[i]*rr[i]*sc;
      bsum += w4[i]*rr[i]*mm[i];
    }
  } else {
    #pragma unroll
    for (int i=0;i<4;i++) vs[i] = w4[i];
  }
  u16 hi[4], lo[4];
  #pragma unroll
  for (int i=0;i<4;i++){
    hi[i] = f2h(vs[i]);
    lo[i] = f2h(vs[i] - h2f(hi[i]));
  }
  size_t idx = ((size_t)(z*8 + (lane>>3))*256 + co)*32 + ((lane>>1)&3)*8 + (lane&1)*4;
  *(uint2*)(wh + idx) = make_uint2((unsigned)hi[0] | ((unsigned)hi[1]<<16),
                                   (unsigned)hi[2] | ((unsigned)hi[3]<<16));
  *(uint2*)(wl + idx) = make_uint2((unsigned)lo[0] | ((unsigned)lo[1]<<16),
                                   (unsigned)lo[2] | ((unsigned)lo[3]<<16));
  #pragma unroll
  for (int off = 32; off >= 1; off >>= 1) bsum += __shfl_down(bsum, off);
  if (lane == 0) bias2[z*256 + co] = sc*(bias[co] - bsum);
}

// ---------------- K2: conv1x1 via MFMA (f16 hi/lo weights, raw f16 inputs) ------
// Block: 64 sp x 256 co, 4 waves (wave = co 64). X tile staged once in LDS
// as [sp 64][kc 256] f16, chunk16 ^ (sp&7) (k_attn-proven read pattern).
// modes 0/1: D[sp][co] = mfma(A=XT, B=W'); mode 2: D[co][sp] = mfma(A=W', B=XT).
__global__ __launch_bounds__(256, 3) void k_conv(
    const float* __restrict__ q, const float* __restrict__ kk,
    const u16* __restrict__ wh, const u16* __restrict__ wl,
    const float* __restrict__ bias2,
    u16* __restrict__ qe, u16* __restrict__ kt, u16* __restrict__ se)
{
  __shared__ u16 XT[64*256];   // 32KB
  const int tid = threadIdx.x;
  const int spt = blockIdx.x, bz = blockIdx.y;
  const int b = bz / 3, mode = bz - b*3;
  const int sp0 = spt*64;
  const float* X = (mode==0 ? q : kk) + (size_t)b*C_*N_;
  const int z = (mode==0) ? b : (mode==1 ? 4+b : 8);
  const u16* whp = wh + (size_t)z*8*256*32;
  const u16* wlp = wl + (size_t)z*8*256*32;
  const float* bp = bias2 + z*256;

  // stage: iter i: kc = i*16 + (t&15), sp-quad = t>>4 (wave covers 16 sp x 16 kc -> coalesced 64B/row)
  {
    int kc_l = tid & 15, spq = tid >> 4;
    #pragma unroll
    for (int i=0;i<16;i++){
      int kc = i*16 + kc_l;
      float4 v = *(const float4*)(X + (size_t)kc*N_ + sp0 + spq*4);
      float vv[4] = {v.x, v.y, v.z, v.w};
      #pragma unroll
      for (int e=0;e<4;e++){
        int sp = spq*4 + e;
        int byte = sp*512 + (((kc>>3) ^ (sp&7)) << 4) + (kc&7)*2;
        *(u16*)((char*)XT + byte) = f2h(vv[e]);
      }
    }
  }
  __syncthreads();

  const int wid = tid>>6, lane = tid&63, l15 = lane&15, lg = lane>>4;
  f32x4 acc[4][4];
  #pragma unroll
  for (int i=0;i<4;i++)
    #pragma unroll
    for (int j=0;j<4;j++) acc[i][j] = (f32x4)(0.f);

  #pragma unroll
  for (int ks=0; ks<8; ++ks){
    half8 xf[4];
    #pragma unroll
    for (int st=0; st<4; ++st)
      xf[st] = *(const half8*)((char*)XT + (st*16 + l15)*512 + (((ks*4+lg) ^ (l15&7)) << 4));
    #pragma unroll
    for (int ct=0; ct<4; ++ct){
      size_t woff = ((size_t)(ks*256 + wid*64 + ct*16 + l15))*32 + lg*8;
      half8 bh = *(const half8*)(whp + woff);
      half8 bl = *(const half8*)(wlp + woff);
      #pragma unroll
      for (int st=0; st<4; ++st){
        if (mode < 2){
          acc[st][ct] = __builtin_amdgcn_mfma_f32_16x16x32_f16(xf[st], bh, acc[st][ct], 0,0,0);
          acc[st][ct] = __builtin_amdgcn_mfma_f32_16x16x32_f16(xf[st], bl, acc[st][ct], 0,0,0);
        } else {
          acc[ct][st] = __builtin_amdgcn_mfma_f32_16x16x32_f16(bh, xf[st], acc[ct][st], 0,0,0);
          acc[ct][st] = __builtin_amdgcn_mfma_f32_16x16x32_f16(bl, xf[st], acc[ct][st], 0,0,0);
        }
      }
    }
  }

  if (mode < 2){
    u16* o = (mode==0 ? qe : kt);
    #pragma unroll
    for (int st=0; st<4; ++st){
      #pragma unroll
      for (int ct=0; ct<4; ++ct){
        int co = wid*64 + ct*16 + l15;
        float bb = bp[co];
        #pragma unroll
        for (int r=0;r<4;r++){
          int sp = sp0 + st*16 + lg*4 + r;
          o[(size_t)(b*N_ + sp)*C_ + co] = f2h(acc[st][ct][r] + bb);
        }
      }
    }
  } else {
    #pragma unroll
    for (int ct=0; ct<4; ++ct){
      #pragma unroll
      for (int st=0; st<4; ++st){
        #pragma unroll
        for (int r=0;r<4;r++){
          int co = wid*64 + ct*16 + lg*4 + r;
          float bb = bp[co];
          se[(size_t)(b*C_ + co)*M_ + sp0 + st*16 + l15] = f2h(acc[ct][st][r] + bb);
        }
      }
    }
  }
}

// ---------------- K3: swapped-QK flash attention + AdaAttN epilogue ----------------
// (unchanged from R6 passing version)
__global__ __launch_bounds__(256, 2) void k_attn(
    const float* __restrict__ q, const float* __restrict__ stq,
    const u16* __restrict__ qe_g, const u16* __restrict__ kt_g,
    const u16* __restrict__ se_g, float* __restrict__ out)
{
  __shared__ u16 KTs[2][KVB*256];     // 16KB x2, chunk16 ^ (row&7)
  __shared__ u16 SEs[2][C_*KVB];      // 16KB x2, chunk16 ^ ((c>>1)&3)
  __shared__ unsigned WTw[QB*16];     // P weights f16, 32 rows x 64B, chunk16 ^ ((row>>1)&3)
  __shared__ float PMX[4][16];
  __shared__ float SRES[QB];
  __shared__ float LRUNS[2][QB];
  __shared__ int FLG[2];

  const int tid = threadIdx.x;
  const int wid = tid >> 6, lane = tid & 63;
  const int l15 = lane & 15, lg = lane >> 4;
  const int qg = wid & 1, mh = wid >> 1;
  const int b = blockIdx.y;
  const int n0 = blockIdx.x * QB;

  half8 qf[8];
  {
    const u16* qb = qe_g + ((size_t)(b*N_ + n0 + qg*16 + l15))*C_;
    #pragma unroll
    for (int ks=0; ks<8; ++ks) qf[ks] = *(const half8*)(qb + ks*32 + lg*8);
  }

  int ktsrc[4], sesrc[4];
  #pragma unroll
  for (int i=0;i<4;i++){
    int g = (i*4 + wid)*64 + lane;
    int row = g >> 5, cin = g & 31;
    ktsrc[i] = row*512 + ((cin ^ (row & 7)) << 4);
    int c = g >> 2, mch = (g & 3) ^ ((c >> 1) & 3);
    sesrc[i] = c*8192 + mch*16;
  }
  const char* ktg = (const char*)kt_g + (size_t)b*M_*512;
  const char* seg = (const char*)se_g + (size_t)b*C_*M_*2;

  float m_run = -1e30f, lrun = 0.f;
  f32x4 accm[2][4], accs[2][4];
  #pragma unroll
  for (int i=0;i<2;i++)
    #pragma unroll
    for (int j=0;j<4;j++){ accm[i][j] = (f32x4)(0.f); accs[i][j] = (f32x4)(0.f); }

  #pragma unroll
  for (int i=0;i<4;i++){
    int o = (i*4 + wid)*1024;
    gll16(ktg + ktsrc[i], (char*)&KTs[0][0] + o);
    gll16(seg + sesrc[i], (char*)&SEs[0][0] + o);
  }

  for (int t=0; t<M_/KVB; ++t){
    const int buf = t & 1;
    __syncthreads();     // B1: full drain (stage(t) complete), prev PV done

    if (t+1 < M_/KVB){
      const int nb = buf ^ 1;
      int koff = (t+1)*(KVB*512);
      int soff = (t+1)*(KVB*2);
      #pragma unroll
      for (int i=0;i<4;i++){
        int o = (i*4 + wid)*1024;
        gll16(ktg + koff + ktsrc[i], (char*)&KTs[nb][0] + o);
        gll16(seg + soff + sesrc[i], (char*)&SEs[nb][0] + o);
      }
    }

    f32x4 L0 = (f32x4)(0.f);
    {
      const char* ktb = (const char*)&KTs[buf][0];
      int krow = mh*16 + l15;
      #pragma unroll
      for (int ks=0; ks<8; ++ks){
        half8 a0 = *(const half8*)(ktb + krow*512 + (((ks*4 + lg) ^ (l15 & 7)) << 4));
        L0 = __builtin_amdgcn_mfma_f32_16x16x32_f16(a0, qf[ks], L0, 0,0,0);
      }
    }
    float pm = fmaxf(fmaxf(L0[0], L0[1]), fmaxf(L0[2], L0[3]));
    pm = fmaxf(pm, __shfl_xor(pm, 16));
    pm = fmaxf(pm, __shfl_xor(pm, 32));
    if (lg == 0) PMX[wid][l15] = pm;
    bar_lds();           // Bmax

    float m_tile = fmaxf(pm, PMX[wid ^ 2][l15]);
    int flag = __any(m_tile > m_run + 8.0f);   // defer-max THR=8 (exp2 domain)
    float sv = 1.0f;
    if (flag){
      float mn = fmaxf(m_run, m_tile);
      sv = exp2f(m_run - mn);
      m_run = mn;
    }
    if (mh == 0 && lg == 0) SRES[qg*16 + l15] = sv;
    if (mh == 0 && lane == 0) FLG[qg] = flag;
    unsigned W0 = pkrtz(exp2f(L0[0]-m_run), exp2f(L0[1]-m_run));
    unsigned W1 = pkrtz(exp2f(L0[2]-m_run), exp2f(L0[3]-m_run));
    {
      int row = qg*16 + l15;
      int c16 = (mh*2 + (lg >> 1)) ^ ((l15 >> 1) & 3);
      *(uint2*)((char*)WTw + row*64 + (c16 << 4) + ((lg & 1) << 3)) = make_uint2(W0, W1);
    }
    float rs = sum2(W0) + sum2(W1);
    rs += __shfl_xor(rs, 16);
    rs += __shfl_xor(rs, 32);
    lrun = lrun * sv + rs;
    bar_lds();           // B2

    if (FLG[0] | FLG[1]){
      #pragma unroll
      for (int rt=0;rt<2;rt++){
        f32x4 s4 = *(const f32x4*)&SRES[rt*16 + lg*4];
        #pragma unroll
        for (int ct=0;ct<4;ct++){
          #pragma unroll
          for (int r=0;r<4;r++){ accm[rt][ct][r] *= s4[r]; accs[rt][ct][r] *= s4[r]; }
        }
      }
    }

    {
      half8 a[2];
      #pragma unroll
      for (int rt=0;rt<2;rt++){
        int row = rt*16 + l15;
        a[rt] = *(const half8*)((char*)WTw + row*64 + ((lg ^ ((l15>>1)&3)) << 4));
      }
      const char* seb = (const char*)&SEs[buf][0];
      #pragma unroll
      for (int ct=0;ct<4;ct++){
        int c = wid*64 + ct*16 + l15;
        half8 v = *(const half8*)(seb + c*64 + ((lg ^ ((c>>1)&3)) << 4));
        half8 h2 = v * v;
        half8 l2;
#if __has_builtin(__builtin_elementwise_fma)
        l2 = __builtin_elementwise_fma(v, v, -h2);
#else
        #pragma unroll
        for (int e=0;e<8;e++){ float vf=(float)v[e]; l2[e]=(_Float16)(vf*vf-(float)h2[e]); }
#endif
        #pragma unroll
        for (int rt=0;rt<2;rt++){
          accm[rt][ct] = __builtin_amdgcn_mfma_f32_16x16x32_f16(a[rt], v,  accm[rt][ct], 0,0,0);
          accs[rt][ct] = __builtin_amdgcn_mfma_f32_16x16x32_f16(a[rt], h2, accs[rt][ct], 0,0,0);
          accs[rt][ct] = __builtin_amdgcn_mfma_f32_16x16x32_f16(a[rt], l2, accs[rt][ct], 0,0,0);
        }
      }
    }
  }

  if (lg == 0) LRUNS[mh][qg*16 + l15] = lrun;
  __syncthreads();

  #pragma unroll
  for (int rt=0;rt<2;rt++){
    f32x4 lv0 = *(const f32x4*)&LRUNS[0][rt*16 + lg*4];
    f32x4 lv1 = *(const f32x4*)&LRUNS[1][rt*16 + lg*4];
    f32x4 inv;
    #pragma unroll
    for (int r=0;r<4;r++) inv[r] = 1.f / (lv0[r] + lv1[r]);
    #pragma unroll
    for (int ct=0;ct<4;ct++){
      int c = wid*64 + ct*16 + l15;
      float2 st = *(const float2*)(stq + (size_t)(b*C_ + c)*2);
      size_t base = ((size_t)(b*C_ + c))*(size_t)N_ + (size_t)(n0 + rt*16 + lg*4);
      f32x4 qv = *(const f32x4*)(q + base);
      f32x4 res;
      #pragma unroll
      for (int r=0;r<4;r++){
        float mean = accm[rt][ct][r] * inv[r];
        float ms   = accs[rt][ct][r] * inv[r];
        float sd   = sqrtf(fmaxf(ms - mean*mean, 0.f));
        float qn   = (qv[r] - st.x) * st.y;
        res[r] = qn * sd + mean;
      }
      *(f32x4*)(out + base) = res;
    }
  }
}

extern "C" void kernel_launch(void* const* d_in, const int* in_sizes, int n_in,
                              void* d_out, int out_size, void* d_ws, size_t ws_size,
                              hipStream_t stream){
  const float* q   = (const float*)d_in[0];
  const float* k   = (const float*)d_in[1];
  const float* wq  = (const float*)d_in[2];
  const float* bq  = (const float*)d_in[3];
  const float* wk  = (const float*)d_in[4];
  const float* bk  = (const float*)d_in[5];
  const float* wsw = (const float*)d_in[6];
  const float* bs  = (const float*)d_in[7];
  float* out = (float*)d_out;

  char* w = (char*)d_ws;
  float* stq = (float*)w;                          // 8KB
  float* stk = (float*)(w + 8192);                 // 8KB
  u16* wh    = (u16*)(w + 16384);                  // 9*8*256*32 u16 = 1.125MB
  u16* wl    = (u16*)(w + 16384 + 1179648);
  float* bias2 = (float*)(w + 16384 + 2*1179648);  // 9*256 f32
  char* big  = w + 16384 + 2*1179648 + 16384;
  u16* qe  = (u16*)big;                            // each B*4096*256 f16 = 8 MB
  u16* kt  = qe + (size_t)B_*N_*C_;
  u16* se  = kt + (size_t)B_*M_*C_;

  k_stats<<<dim3(2048), dim3(256), 0, stream>>>(q, k, stq, stk);
  k_wprep<<<dim3(256, 9), dim3(64), 0, stream>>>(wq, bq, wk, bk, wsw, bs,
                                                 stq, stk, wh, wl, bias2);
  k_conv<<<dim3(64, 12), dim3(256), 0, stream>>>(q, k, wh, wl, bias2, qe, kt, se);
  k_attn<<<dim3(N_/QB, B_), dim3(256), 0, stream>>>(q, stq, qe, kt, se, out);
}